// Round 1
// baseline (11337.964 us; speedup 1.0000x reference)
//
#include <hip/hip_runtime.h>
#include <stdint.h>

#define TSTEPS 512
#define NWG 192

typedef short s8v __attribute__((ext_vector_type(8)));
typedef float f4v __attribute__((ext_vector_type(4)));

// ---- workspace layout (bytes) ----
#define WP_BYTES  37748736ull               // packed weights bf16, fragment order
#define XP_BYTES 100663296ull               // packed x bf16, fragment-granule order
#define HS_BYTES    393216ull               // h state, 2 x [64][1536] bf16 (transposed)
#define WP_OFF 0ull
#define XP_OFF (WP_OFF + WP_BYTES)
#define HS_OFF (XP_OFF + XP_BYTES)
#define CNT_OFF (HS_OFF + HS_BYTES)
#define WS_NEEDED (CNT_OFF + 256ull)

// ---- LDS layout (dynamic, 147456 B) ----
#define LDS_H  0            // 98304 B: h-part of z, fragment order (48 ksteps x 2 cf x 1KB)
#define LDS_X0 98304        // 24576 B: x chunk buffer 0 (12 ksteps x 2 cf x 1KB)
#define LDS_X1 122880       // 24576 B: x chunk buffer 1
#define LDS_TOTAL 147456

__device__ __forceinline__ uint16_t f2bf(float f) {
  union { float f; uint32_t u; } v; v.f = f;
  uint32_t u = v.u;
  return (uint16_t)((u + 0x7fffu + ((u >> 16) & 1u)) >> 16);
}
__device__ __forceinline__ float sigm(float x) { return 1.0f / (1.0f + __expf(-x)); }
__device__ __forceinline__ float tanh_fast(float x) {
  float e = __expf(2.0f * x);
  return 1.0f - 2.0f / (e + 1.0f);   // graceful at +/-inf
}

__device__ __forceinline__ void gload_lds16(const void* g, void* l) {
  typedef __attribute__((address_space(1))) uint32_t g32;
  typedef __attribute__((address_space(3))) uint32_t l32;
  __builtin_amdgcn_global_load_lds((g32*)g, (l32*)l, 16, 0, 0);
}

// ============ prep kernels ============

// Pack W{f,i,o,c} fp32 [1536][3072] -> bf16 fragment tiles.
// tile index = ((rg*96 + ks)*4 + g); within tile: lane l holds 16B =
// W_g[rg*16 + (l&15)][ks*32 + (l>>4)*8 + j], j=0..7
__global__ void pack_w(const float* __restrict__ Wf, const float* __restrict__ Wi,
                       const float* __restrict__ Wo, const float* __restrict__ Wc,
                       uint16_t* __restrict__ wp) {
  int tile = blockIdx.x * 4 + (threadIdx.x >> 6);
  int lane = threadIdx.x & 63;
  int g  = tile & 3;
  int ks = (tile >> 2) % 96;
  int rg = tile / 384;
  const float* W = (g == 0) ? Wf : (g == 1) ? Wi : (g == 2) ? Wo : Wc;
  int hr = rg * 16 + (lane & 15);
  int kk = ks * 32 + (lane >> 4) * 8;
  const float* src = W + (size_t)hr * 3072 + kk;
  uint32_t w[4];
#pragma unroll
  for (int j = 0; j < 4; ++j) {
    uint32_t lo = f2bf(src[2 * j]);
    uint32_t hi = f2bf(src[2 * j + 1]);
    w[j] = lo | (hi << 16);
  }
  *(uint4*)((char*)wp + (size_t)tile * 1024 + (size_t)lane * 16) = make_uint4(w[0], w[1], w[2], w[3]);
}

// Pack x fp32 [T][1536][64] -> bf16 fragment granules:
// global granule gi = (((t*2+ch)*48 + xks)*2 + cf)*64 + lane; 16B =
// x[t][xks*32 + (lane>>4)*8 + j][ch*32 + cf*16 + (lane&15)]
__global__ void pack_x(const float* __restrict__ x, uint16_t* __restrict__ xp) {
  size_t gi = (size_t)blockIdx.x * 256 + threadIdx.x;   // < 6291456
  int lane = (int)(gi & 63);
  size_t r1 = gi >> 6;
  int cf = (int)(r1 & 1);
  size_t r2 = r1 >> 1;
  int xks = (int)(r2 % 48);
  size_t r3 = r2 / 48;
  int ch = (int)(r3 & 1);
  int t  = (int)(r3 >> 1);
  int c  = ch * 32 + cf * 16 + (lane & 15);
  int i0 = xks * 32 + (lane >> 4) * 8;
  const float* src = x + ((size_t)t * 1536 + i0) * 64 + c;
  uint32_t w[4];
#pragma unroll
  for (int j = 0; j < 4; ++j) {
    uint32_t lo = f2bf(src[(size_t)(2 * j) * 64]);
    uint32_t hi = f2bf(src[(size_t)(2 * j + 1) * 64]);
    w[j] = lo | (hi << 16);
  }
  *(uint4*)((char*)xp + gi * 16) = make_uint4(w[0], w[1], w[2], w[3]);
}

// h0 fp32 [1536][64] -> hstate buffer 0, transposed bf16 [64][1536]
__global__ void pack_h0(const float* __restrict__ h0, uint16_t* __restrict__ hs) {
  int e = blockIdx.x * 256 + threadIdx.x;   // < 98304
  int c = e / 1536, hr = e % 1536;
  hs[e] = f2bf(h0[(size_t)hr * 64 + c]);
}

// ============ persistent LSTM kernel ============
// 192 blocks x 256 threads. block b: ch = b/96 (column half, cols ch*32..+31),
// rg = b%96 (h-rows rg*16..+15). wave w computes gate w: 16 rows x 32 cols,
// 2 col-fragments, K=3072 (h part ks 0..47 from LDS_H, x part ks 48..95 from X buffers).
__global__ __launch_bounds__(256) void lstm_persist(
    const float* __restrict__ bfp, const float* __restrict__ bip,
    const float* __restrict__ bop, const float* __restrict__ bcp,
    const float* __restrict__ c0p,
    const uint16_t* __restrict__ wp, const uint16_t* __restrict__ xp,
    uint16_t* __restrict__ hstate, int* __restrict__ cnt,
    float* __restrict__ out)
{
  extern __shared__ char lds[];
  const int tid = threadIdx.x;
  const int wave = tid >> 6, lane = tid & 63;
  const int b = blockIdx.x;
  const int ch = b / 96, rg = b % 96;   // pair (rg,0),(rg,1) -> same XCD (b, b+96: same %8)

  const int e1 = tid + 256;
  const int r0 = tid >> 5, cl0 = tid & 31;
  const int r1e = e1 >> 5, cl1 = e1 & 31;
  const int hr0 = rg * 16 + r0, hr1 = rg * 16 + r1e;
  const int cg0 = ch * 32 + cl0, cg1 = ch * 32 + cl1;

  float cst0 = c0p[(size_t)hr0 * 64 + cg0];
  float cst1 = c0p[(size_t)hr1 * 64 + cg1];
  const float vbf0 = bfp[hr0], vbi0 = bip[hr0], vbo0 = bop[hr0], vbc0 = bcp[hr0];
  const float vbf1 = bfp[hr1], vbi1 = bip[hr1], vbo1 = bop[hr1], vbc1 = bcp[hr1];

  const char* wpb = (const char*)wp;
  const size_t a_base = ((size_t)rg * 384 + wave) * 1024 + (size_t)lane * 16;
  const char* xpb = (const char*)xp;

  for (int t = 0; t < TSTEPS; ++t) {
    const int par = t & 1;

    // ---- issue x chunks 0,1 (async global->LDS, granule-linear) ----
    {
      const size_t tc = ((size_t)t * 2 + ch) * 6144;
#pragma unroll
      for (int q = 0; q < 2; ++q) {
        const char* gb = xpb + (tc + (size_t)q * 1536) * 16;
        char* lb = lds + (q ? LDS_X1 : LDS_X0) + wave * 1024;
#pragma unroll
        for (int i = 0; i < 6; ++i)
          gload_lds16(gb + (size_t)(i * 256 + tid) * 16, lb + i * 4096);
      }
    }

    // ---- stage h-part of z into LDS via coherent (system-scope) loads ----
    {
      const uint16_t* hsrc = hstate + (size_t)par * 98304;
#pragma unroll
      for (int i = 0; i < 24; ++i) {
        int gi = i * 256 + tid;
        int lg = gi & 63;
        int tl = gi >> 6;            // (ks*2 + cf)
        int cf = tl & 1, ks = tl >> 1;
        int cg = ch * 32 + cf * 16 + (lg & 15);
        int k0 = ks * 32 + (lg >> 4) * 8;
        unsigned long long* p = (unsigned long long*)(hsrc + (size_t)cg * 1536 + k0);
        unsigned long long v0 = __hip_atomic_load(p,     __ATOMIC_RELAXED, __HIP_MEMORY_SCOPE_SYSTEM);
        unsigned long long v1 = __hip_atomic_load(p + 1, __ATOMIC_RELAXED, __HIP_MEMORY_SCOPE_SYSTEM);
        uint4 w;
        *(unsigned long long*)&w.x = v0;
        *(unsigned long long*)&w.z = v1;
        *(uint4*)(lds + LDS_H + (size_t)gi * 16) = w;
      }
    }

    __syncthreads();   // h staged; x chunks 0,1 drained (vmcnt)

    f4v acc0 = {0.f, 0.f, 0.f, 0.f};
    f4v acc1 = {0.f, 0.f, 0.f, 0.f};
    const char* ab = wpb + a_base;

    // ---- h phase: ks 0..47, reg-double-buffered A prefetch ----
    {
      uint4 curA[8], nxtA[8];
#pragma unroll
      for (int i = 0; i < 8; ++i) curA[i] = *(const uint4*)(ab + (size_t)i * 4096);
      for (int c8 = 0; c8 < 6; ++c8) {
        if (c8 < 5) {
#pragma unroll
          for (int i = 0; i < 8; ++i)
            nxtA[i] = *(const uint4*)(ab + (size_t)((c8 + 1) * 8 + i) * 4096);
        }
#pragma unroll
        for (int i = 0; i < 8; ++i) {
          int ks = c8 * 8 + i;
          uint4 b0 = *(const uint4*)(lds + LDS_H + (size_t)(ks * 2 + 0) * 1024 + lane * 16);
          uint4 b1 = *(const uint4*)(lds + LDS_H + (size_t)(ks * 2 + 1) * 1024 + lane * 16);
          acc0 = __builtin_amdgcn_mfma_f32_16x16x32_bf16(
                   __builtin_bit_cast(s8v, curA[i]), __builtin_bit_cast(s8v, b0), acc0, 0, 0, 0);
          acc1 = __builtin_amdgcn_mfma_f32_16x16x32_bf16(
                   __builtin_bit_cast(s8v, curA[i]), __builtin_bit_cast(s8v, b1), acc1, 0, 0, 0);
        }
#pragma unroll
        for (int i = 0; i < 8; ++i) curA[i] = nxtA[i];
      }
    }

    // ---- x phases: 4 x 12 ksteps ----
    auto consume12 = [&](int ksbase, int ldsbase) {
      const char* ab2 = ab + (size_t)ksbase * 4096;
      uint4 cA[6], nA[6];
#pragma unroll
      for (int i = 0; i < 6; ++i) cA[i] = *(const uint4*)(ab2 + (size_t)i * 4096);
#pragma unroll
      for (int i = 0; i < 6; ++i) nA[i] = *(const uint4*)(ab2 + (size_t)(6 + i) * 4096);
#pragma unroll
      for (int i = 0; i < 6; ++i) {
        uint4 b0 = *(const uint4*)(lds + ldsbase + (size_t)(i * 2 + 0) * 1024 + lane * 16);
        uint4 b1 = *(const uint4*)(lds + ldsbase + (size_t)(i * 2 + 1) * 1024 + lane * 16);
        acc0 = __builtin_amdgcn_mfma_f32_16x16x32_bf16(
                 __builtin_bit_cast(s8v, cA[i]), __builtin_bit_cast(s8v, b0), acc0, 0, 0, 0);
        acc1 = __builtin_amdgcn_mfma_f32_16x16x32_bf16(
                 __builtin_bit_cast(s8v, cA[i]), __builtin_bit_cast(s8v, b1), acc1, 0, 0, 0);
      }
#pragma unroll
      for (int i = 0; i < 6; ++i) {
        uint4 b0 = *(const uint4*)(lds + ldsbase + (size_t)((6 + i) * 2 + 0) * 1024 + lane * 16);
        uint4 b1 = *(const uint4*)(lds + ldsbase + (size_t)((6 + i) * 2 + 1) * 1024 + lane * 16);
        acc0 = __builtin_amdgcn_mfma_f32_16x16x32_bf16(
                 __builtin_bit_cast(s8v, nA[i]), __builtin_bit_cast(s8v, b0), acc0, 0, 0, 0);
        acc1 = __builtin_amdgcn_mfma_f32_16x16x32_bf16(
                 __builtin_bit_cast(s8v, nA[i]), __builtin_bit_cast(s8v, b1), acc1, 0, 0, 0);
      }
    };
    auto issue_chunk = [&](int q) {
      const size_t tc = ((size_t)t * 2 + ch) * 6144;
      const char* gb = xpb + (tc + (size_t)q * 1536) * 16;
      char* lb = lds + ((q & 1) ? LDS_X1 : LDS_X0) + wave * 1024;
#pragma unroll
      for (int i = 0; i < 6; ++i)
        gload_lds16(gb + (size_t)(i * 256 + tid) * 16, lb + i * 4096);
    };

    consume12(48, LDS_X0);
    __syncthreads();
    issue_chunk(2);
    consume12(60, LDS_X1);
    __syncthreads();
    issue_chunk(3);
    consume12(72, LDS_X0);
    __syncthreads();               // drains chunk 3
    consume12(84, LDS_X1);

    // ---- gate preactivations -> LDS (X0 region is free now) ----
    {
      float* pre = (float*)(lds + LDS_X0);
#pragma unroll
      for (int reg = 0; reg < 4; ++reg) {
        int r = (lane >> 4) * 4 + reg;        // D row = (lane>>4)*4 + reg
        int cc = (lane & 15);                 // D col = lane & 15
        pre[wave * 512 + r * 32 + cc]      = acc0[reg];
        pre[wave * 512 + r * 32 + 16 + cc] = acc1[reg];
      }
    }
    __syncthreads();

    // ---- pointwise gates, c/h update ----
    float hv0, hv1;
    {
      const float* pre = (const float*)(lds + LDS_X0);
      float pf = pre[0 * 512 + r0 * 32 + cl0] + vbf0;
      float pi = pre[1 * 512 + r0 * 32 + cl0] + vbi0;
      float po = pre[2 * 512 + r0 * 32 + cl0] + vbo0;
      float pc = pre[3 * 512 + r0 * 32 + cl0] + vbc0;
      float f = sigm(pf), ii = sigm(pi), o = sigm(po), cc = tanh_fast(pc);
      cst0 = f * cst0 + ii * cc;
      hv0 = o * tanh_fast(cst0);
      pf = pre[0 * 512 + r1e * 32 + cl1] + vbf1;
      pi = pre[1 * 512 + r1e * 32 + cl1] + vbi1;
      po = pre[2 * 512 + r1e * 32 + cl1] + vbo1;
      pc = pre[3 * 512 + r1e * 32 + cl1] + vbc1;
      f = sigm(pf); ii = sigm(pi); o = sigm(po); cc = tanh_fast(pc);
      cst1 = f * cst1 + ii * cc;
      hv1 = o * tanh_fast(cst1);
    }
    out[((size_t)t * 1536 + hr0) * 64 + cg0] = hv0;
    out[((size_t)t * 1536 + hr1) * 64 + cg1] = hv1;

    // ---- transpose h into LDS (X1 region, stride 24 for bank spread) ----
    {
      uint16_t* ht = (uint16_t*)(lds + LDS_X1);
      ht[cl0 * 24 + r0]  = f2bf(hv0);
      ht[cl1 * 24 + r1e] = f2bf(hv1);
    }
    __syncthreads();

    // ---- coherent write of h slice to hstate[par^1] ----
    if (tid < 64) {
      int c_l = tid >> 1, half = tid & 1;
      uint4 v = *(const uint4*)(lds + LDS_X1 + ((size_t)c_l * 24 + half * 8) * 2);
      unsigned long long lo = *(unsigned long long*)&v.x;
      unsigned long long hi = *(unsigned long long*)&v.z;
      size_t off = (size_t)(par ^ 1) * 98304 + (size_t)(ch * 32 + c_l) * 1536 + rg * 16 + half * 8;
      unsigned long long* dp = (unsigned long long*)(hstate + off);
      __hip_atomic_store(dp,     lo, __ATOMIC_RELAXED, __HIP_MEMORY_SCOPE_SYSTEM);
      __hip_atomic_store(dp + 1, hi, __ATOMIC_RELAXED, __HIP_MEMORY_SCOPE_SYSTEM);
    }
    __syncthreads();   // drains the coherent stores (vmcnt) before signaling

    // ---- grid epoch barrier ----
    if (tid == 0) {
      __hip_atomic_fetch_add(cnt, 1, __ATOMIC_RELAXED, __HIP_MEMORY_SCOPE_SYSTEM);
      const int target = NWG * (t + 1);
      while (__hip_atomic_load(cnt, __ATOMIC_RELAXED, __HIP_MEMORY_SCOPE_SYSTEM) < target)
        __builtin_amdgcn_s_sleep(1);
    }
    __syncthreads();
  }
}

// ============ host launcher ============
extern "C" void kernel_launch(void* const* d_in, const int* in_sizes, int n_in,
                              void* d_out, int out_size, void* d_ws, size_t ws_size,
                              hipStream_t stream) {
  (void)in_sizes; (void)n_in; (void)out_size;
  const float* x   = (const float*)d_in[0];
  const float* Wf  = (const float*)d_in[1];
  const float* bf_ = (const float*)d_in[2];
  const float* Wi  = (const float*)d_in[3];
  const float* bi_ = (const float*)d_in[4];
  const float* Wo  = (const float*)d_in[5];
  const float* bo_ = (const float*)d_in[6];
  const float* Wc  = (const float*)d_in[7];
  const float* bc_ = (const float*)d_in[8];
  const float* h0  = (const float*)d_in[9];
  const float* c0  = (const float*)d_in[10];

  if (ws_size < WS_NEEDED) return;   // diagnostic: clean absmax fail (not a crash) if ws too small

  char* ws = (char*)d_ws;
  uint16_t* wp = (uint16_t*)(ws + WP_OFF);
  uint16_t* xp = (uint16_t*)(ws + XP_OFF);
  uint16_t* hs = (uint16_t*)(ws + HS_OFF);
  int* cnt     = (int*)(ws + CNT_OFF);

  hipMemsetAsync(cnt, 0, 256, stream);
  pack_w<<<9216, 256, 0, stream>>>(Wf, Wi, Wo, Wc, wp);
  pack_x<<<24576, 256, 0, stream>>>(x, xp);
  pack_h0<<<384, 256, 0, stream>>>(h0, hs);

  hipFuncSetAttribute(reinterpret_cast<const void*>(lstm_persist),
                      hipFuncAttributeMaxDynamicSharedMemorySize, LDS_TOTAL);
  lstm_persist<<<NWG, 256, LDS_TOTAL, stream>>>(bf_, bi_, bo_, bc_, c0,
                                                wp, xp, hs, cnt, (float*)d_out);
}

// Round 2
// 8339.497 us; speedup vs baseline: 1.3596x; 1.3596x over previous
//
#include <hip/hip_runtime.h>
#include <stdint.h>

#define TSTEPS 512
#define NWG 192

typedef short s8v __attribute__((ext_vector_type(8)));
typedef float f4v __attribute__((ext_vector_type(4)));

// ---- workspace layout (bytes) ----
#define WP_BYTES  37748736ull               // packed weights bf16 (full K), fragment tiles
#define XP_BYTES 100663296ull               // packed x bf16 (mode-specific layout, same size)
#define GX_BYTES 402653184ull               // gx = Wx@x, bf16 [T][6144][64]  (mode A only)
#define HS_BYTES    393216ull               // h state, 2 x [64][1536] bf16 (transposed)
#define WP_OFF 0ull
#define XP_OFF 37748736ull
#define GX_OFF 138412032ull
#define HS_A_OFF (GX_OFF + GX_BYTES)
#define FL_A_OFF (HS_A_OFF + HS_BYTES)
#define WS_A_NEEDED (FL_A_OFF + 1024ull)    // ~516.6 MiB
#define HS_B_OFF 138412032ull
#define FL_B_OFF (HS_B_OFF + HS_BYTES)
#define WS_B_NEEDED (FL_B_OFF + 1024ull)    // ~132.4 MiB (proven available)

// ---- LDS layout (dynamic, 147456 B) ----
#define LDS_H  0            // 98304 B: h-part of z, fragment order (48 ksteps x 2 cf x 1KB)
#define LDS_X0 98304        // 24576 B: x chunk buffer 0 / gate-preact scratch
#define LDS_X1 122880       // 24576 B: x chunk buffer 1 / h-transpose scratch
#define LDS_TOTAL 147456

__device__ __forceinline__ uint16_t f2bf(float f) {
  union { float f; uint32_t u; } v; v.f = f;
  uint32_t u = v.u;
  return (uint16_t)((u + 0x7fffu + ((u >> 16) & 1u)) >> 16);
}
__device__ __forceinline__ float bf2f(uint32_t u) {
  union { uint32_t u; float f; } v; v.u = u << 16;
  return v.f;
}
__device__ __forceinline__ float sigm(float x) { return 1.0f / (1.0f + __expf(-x)); }
__device__ __forceinline__ float tanh_fast(float x) {
  float e = __expf(2.0f * x);
  return 1.0f - 2.0f / (e + 1.0f);
}

__device__ __forceinline__ void gload_lds16(const void* g, void* l) {
  typedef __attribute__((address_space(1))) uint32_t g32;
  typedef __attribute__((address_space(3))) uint32_t l32;
  __builtin_amdgcn_global_load_lds((g32*)g, (l32*)l, 16, 0, 0);
}

// ============ prep kernels ============

// Pack W{f,i,o,c} fp32 [1536][3072] -> bf16 fragment tiles (full K).
// tile id = ((rg*96 + ks)*4 + g); lane l holds 16B =
// W_g[rg*16 + (l&15)][ks*32 + (l>>4)*8 + j], j=0..7
__global__ void pack_w(const float* __restrict__ Wf, const float* __restrict__ Wi,
                       const float* __restrict__ Wo, const float* __restrict__ Wc,
                       uint16_t* __restrict__ wp) {
  int tile = blockIdx.x * 4 + (threadIdx.x >> 6);
  int lane = threadIdx.x & 63;
  int g  = tile & 3;
  int ks = (tile >> 2) % 96;
  int rg = tile / 384;
  const float* W = (g == 0) ? Wf : (g == 1) ? Wi : (g == 2) ? Wo : Wc;
  int hr = rg * 16 + (lane & 15);
  int kk = ks * 32 + (lane >> 4) * 8;
  const float* src = W + (size_t)hr * 3072 + kk;
  uint32_t w[4];
#pragma unroll
  for (int j = 0; j < 4; ++j) {
    uint32_t lo = f2bf(src[2 * j]);
    uint32_t hi = f2bf(src[2 * j + 1]);
    w[j] = lo | (hi << 16);
  }
  *(uint4*)((char*)wp + (size_t)tile * 1024 + (size_t)lane * 16) = make_uint4(w[0], w[1], w[2], w[3]);
}

// Mode B: pack x for in-loop consumption (round-1 layout).
__global__ void pack_x(const float* __restrict__ x, uint16_t* __restrict__ xp) {
  size_t gi = (size_t)blockIdx.x * 256 + threadIdx.x;   // < 6291456
  int lane = (int)(gi & 63);
  size_t r1 = gi >> 6;
  int cf = (int)(r1 & 1);
  size_t r2 = r1 >> 1;
  int xks = (int)(r2 % 48);
  size_t r3 = r2 / 48;
  int ch = (int)(r3 & 1);
  int t  = (int)(r3 >> 1);
  int c  = ch * 32 + cf * 16 + (lane & 15);
  int i0 = xks * 32 + (lane >> 4) * 8;
  const float* src = x + ((size_t)t * 1536 + i0) * 64 + c;
  uint32_t w[4];
#pragma unroll
  for (int j = 0; j < 4; ++j) {
    uint32_t lo = f2bf(src[(size_t)(2 * j) * 64]);
    uint32_t hi = f2bf(src[(size_t)(2 * j + 1) * 64]);
    w[j] = lo | (hi << 16);
  }
  *(uint4*)((char*)xp + gi * 16) = make_uint4(w[0], w[1], w[2], w[3]);
}

// Mode A: pack x as GEMM B-fragment granules. granule gi = n16*48 + ks;
// lane l: col n = n16*16 + (l&15) -> t=n>>6, b=n&63; k-row i = ks*32+(l>>4)*8+j
__global__ void pack_xg(const float* __restrict__ x, uint16_t* __restrict__ xg) {
  size_t gi4 = (size_t)blockIdx.x * 4 + (threadIdx.x >> 6);  // granule, < 98304
  int lane = threadIdx.x & 63;
  int n16 = (int)(gi4 / 48);
  int ks  = (int)(gi4 % 48);
  int n = n16 * 16 + (lane & 15);
  int t = n >> 6, bb = n & 63;
  int i0 = ks * 32 + (lane >> 4) * 8;
  const float* src = x + ((size_t)t * 1536 + i0) * 64 + bb;
  uint32_t w[4];
#pragma unroll
  for (int j = 0; j < 4; ++j) {
    uint32_t lo = f2bf(src[(size_t)(2 * j) * 64]);
    uint32_t hi = f2bf(src[(size_t)(2 * j + 1) * 64]);
    w[j] = lo | (hi << 16);
  }
  *(uint4*)((char*)xg + gi4 * 1024 + (size_t)lane * 16) = make_uint4(w[0], w[1], w[2], w[3]);
}

// h0 fp32 [1536][64] -> hstate buffer 0, transposed bf16 [64][1536]
__global__ void pack_h0(const float* __restrict__ h0, uint16_t* __restrict__ hs) {
  int e = blockIdx.x * 256 + threadIdx.x;   // < 98304
  int c = e / 1536, hr = e % 1536;
  hs[e] = f2bf(h0[(size_t)hr * 64 + c]);
}

// ============ Mode A: gx = Wx @ X  (M=6144, N=32768, K=1536) ============
// 128x128 tile, 256 threads (4 waves 2x2), BK=32, double-buffered LDS stage
// via global_load_lds. A read from wp's x-half tiles (ks_w = 48+ks).
__global__ __launch_bounds__(256) void gemm_gx(const uint16_t* __restrict__ wp,
                                               const uint16_t* __restrict__ xg,
                                               uint16_t* __restrict__ gxp) {
  __shared__ char lds[32768];   // [buf][A 8KB | B 8KB]
  const int tid = threadIdx.x;
  const int lane = tid & 63, wave = tid >> 6;
  const int bid = blockIdx.x;             // bid = mb*256 + nb
  const int mb = bid >> 8;                // 0..47
  const int nb = bid & 255;               // 0..255
  const int wm = wave >> 1, wn = wave & 1;

  const char* wpb = (const char*)wp;
  const char* xgb = (const char*)xg;
  const int g   = (mb * 8) / 96;          // 8-mt block never crosses a gate (96%8==0)
  const int rgb = (mb * 8) % 96;

  auto stage = [&](int ks, int buf) {
    char* Ad = lds + buf * 16384 + wave * 1024;
    char* Bd = lds + buf * 16384 + 8192 + wave * 1024;
#pragma unroll
    for (int p = 0; p < 2; ++p) {
      int l = wave + p * 4;
      size_t atile = ((size_t)(rgb + l) * 96 + 48 + ks) * 4 + g;
      gload_lds16(wpb + atile * 1024 + (size_t)lane * 16, Ad + p * 4096);
      size_t btile = (size_t)(nb * 8 + l) * 48 + ks;
      gload_lds16(xgb + btile * 1024 + (size_t)lane * 16, Bd + p * 4096);
    }
  };

  stage(0, 0);
  __syncthreads();

  f4v acc[4][4];
#pragma unroll
  for (int i = 0; i < 4; ++i)
#pragma unroll
    for (int j = 0; j < 4; ++j) acc[i][j] = f4v{0.f, 0.f, 0.f, 0.f};

  for (int ks = 0; ks < 48; ++ks) {
    int buf = ks & 1;
    if (ks < 47) stage(ks + 1, buf ^ 1);
    const char* Ab = lds + buf * 16384 + (size_t)(wm * 4) * 1024;
    const char* Bb = lds + buf * 16384 + 8192 + (size_t)(wn * 4) * 1024;
    uint4 af[4], bfr[4];
#pragma unroll
    for (int i = 0; i < 4; ++i) af[i]  = *(const uint4*)(Ab + (size_t)i * 1024 + (size_t)lane * 16);
#pragma unroll
    for (int j = 0; j < 4; ++j) bfr[j] = *(const uint4*)(Bb + (size_t)j * 1024 + (size_t)lane * 16);
#pragma unroll
    for (int i = 0; i < 4; ++i)
#pragma unroll
      for (int j = 0; j < 4; ++j)
        acc[i][j] = __builtin_amdgcn_mfma_f32_16x16x32_bf16(
            __builtin_bit_cast(s8v, af[i]), __builtin_bit_cast(s8v, bfr[j]), acc[i][j], 0, 0, 0);
    __syncthreads();
  }

#pragma unroll
  for (int i = 0; i < 4; ++i) {
    int m = (mb * 8 + wm * 4 + i) * 16 + (lane >> 4) * 4;
#pragma unroll
    for (int j = 0; j < 4; ++j) {
      int n = (nb * 8 + wn * 4 + j) * 16 + (lane & 15);
      int tt = n >> 6, bb = n & 63;
#pragma unroll
      for (int r = 0; r < 4; ++r)
        gxp[((size_t)tt * 6144 + m + r) * 64 + bb] = f2bf(acc[i][j][r]);
    }
  }
}

// ============ persistent LSTM kernel ============
// 192 blocks x 256 threads. block b: ch = b/96, rg = b%96. wave w = gate w.
// Mode A (gxp != null): K=1536 h-part only, gx added in epilogue.
// Mode B (gxp == null): full K=3072 with in-loop x streaming.
__global__ __launch_bounds__(256) void lstm_persist(
    const float* __restrict__ bfp, const float* __restrict__ bip,
    const float* __restrict__ bop, const float* __restrict__ bcp,
    const float* __restrict__ c0p,
    const uint16_t* __restrict__ wp, const uint16_t* __restrict__ xp,
    const uint16_t* __restrict__ gxp,
    uint16_t* __restrict__ hstate, int* __restrict__ flags,
    float* __restrict__ out)
{
  extern __shared__ char lds[];
  const int tid = threadIdx.x;
  const int wave = tid >> 6, lane = tid & 63;
  const int b = blockIdx.x;
  const int ch = b / 96, rg = b % 96;

  const int r0 = tid >> 5, cl0 = tid & 31;     // elem0: row r0, col cl0; elem1: row r0+8
  const int hr0 = rg * 16 + r0, hr1 = hr0 + 8;
  const int cg0 = ch * 32 + cl0;

  float cst0 = c0p[(size_t)hr0 * 64 + cg0];
  float cst1 = c0p[(size_t)hr1 * 64 + cg0];
  const float vbf0 = bfp[hr0], vbi0 = bip[hr0], vbo0 = bop[hr0], vbc0 = bcp[hr0];
  const float vbf1 = bfp[hr1], vbi1 = bip[hr1], vbo1 = bop[hr1], vbc1 = bcp[hr1];

  const char* wpb = (const char*)wp;
  const size_t a_base = ((size_t)rg * 384 + wave) * 1024 + (size_t)lane * 16;
  const char* xpb = (const char*)xp;
  const bool modeA = (gxp != nullptr);

  for (int t = 0; t < TSTEPS; ++t) {
    const int par = t & 1;

    // ---- gx prefetch (mode A): 8 bf16/thread, issued before the wait ----
    uint32_t gxr[8];
    if (modeA) {
      const uint16_t* gbase = gxp + ((size_t)t * 6144 + hr0) * 64 + cg0;
#pragma unroll
      for (int gg = 0; gg < 4; ++gg) {
#pragma unroll
        for (int s = 0; s < 2; ++s)
          gxr[gg * 2 + s] = gbase[((size_t)gg * 1536 + s * 8) * 64];
      }
    }

    // ---- flag barrier: wait until all blocks published h for step t ----
    if (t > 0 && wave == 0) {
      const int need = t;
      for (;;) {
        int ok;
        if (lane < 48) {
          const int* fp = flags + lane * 4;
          int a0 = __hip_atomic_load(fp + 0, __ATOMIC_RELAXED, __HIP_MEMORY_SCOPE_SYSTEM);
          int a1 = __hip_atomic_load(fp + 1, __ATOMIC_RELAXED, __HIP_MEMORY_SCOPE_SYSTEM);
          int a2 = __hip_atomic_load(fp + 2, __ATOMIC_RELAXED, __HIP_MEMORY_SCOPE_SYSTEM);
          int a3 = __hip_atomic_load(fp + 3, __ATOMIC_RELAXED, __HIP_MEMORY_SCOPE_SYSTEM);
          int mn = a0 < a1 ? a0 : a1;
          mn = mn < a2 ? mn : a2;
          mn = mn < a3 ? mn : a3;
          ok = (mn >= need);
        } else ok = 1;
        if (__all(ok)) break;
        __builtin_amdgcn_s_sleep(2);
      }
    }
    __syncthreads();

    // ---- mode B: issue x chunks 0,1 (async global->LDS) ----
    if (!modeA) {
      const size_t tc = ((size_t)t * 2 + ch) * 6144;
#pragma unroll
      for (int q = 0; q < 2; ++q) {
        const char* gb = xpb + (tc + (size_t)q * 1536) * 16;
        char* lb = lds + (q ? LDS_X1 : LDS_X0) + wave * 1024;
#pragma unroll
        for (int i = 0; i < 6; ++i)
          gload_lds16(gb + (size_t)(i * 256 + tid) * 16, lb + i * 4096);
      }
    }

    // ---- stage h-part of z into LDS via coherent loads ----
    {
      const uint16_t* hsrc = hstate + (size_t)par * 98304;
#pragma unroll
      for (int i = 0; i < 24; ++i) {
        int gi = i * 256 + tid;
        int lg = gi & 63;
        int tl = gi >> 6;            // (ks*2 + cf)
        int cf = tl & 1, ks = tl >> 1;
        int cg = ch * 32 + cf * 16 + (lg & 15);
        int k0 = ks * 32 + (lg >> 4) * 8;
        unsigned long long* p = (unsigned long long*)(hsrc + (size_t)cg * 1536 + k0);
        unsigned long long v0 = __hip_atomic_load(p,     __ATOMIC_RELAXED, __HIP_MEMORY_SCOPE_SYSTEM);
        unsigned long long v1 = __hip_atomic_load(p + 1, __ATOMIC_RELAXED, __HIP_MEMORY_SCOPE_SYSTEM);
        uint4 w;
        *(unsigned long long*)&w.x = v0;
        *(unsigned long long*)&w.z = v1;
        *(uint4*)(lds + LDS_H + (size_t)gi * 16) = w;
      }
    }

    __syncthreads();   // h staged; mode-B x chunks 0,1 drained

    f4v acc0 = {0.f, 0.f, 0.f, 0.f};
    f4v acc1 = {0.f, 0.f, 0.f, 0.f};
    const char* ab = wpb + a_base;

    // ---- h phase: ks 0..47, reg-double-buffered A prefetch ----
    {
      uint4 curA[8], nxtA[8];
#pragma unroll
      for (int i = 0; i < 8; ++i) curA[i] = *(const uint4*)(ab + (size_t)i * 4096);
      for (int c8 = 0; c8 < 6; ++c8) {
        if (c8 < 5) {
#pragma unroll
          for (int i = 0; i < 8; ++i)
            nxtA[i] = *(const uint4*)(ab + (size_t)((c8 + 1) * 8 + i) * 4096);
        }
#pragma unroll
        for (int i = 0; i < 8; ++i) {
          int ks = c8 * 8 + i;
          uint4 b0 = *(const uint4*)(lds + LDS_H + (size_t)(ks * 2 + 0) * 1024 + lane * 16);
          uint4 b1 = *(const uint4*)(lds + LDS_H + (size_t)(ks * 2 + 1) * 1024 + lane * 16);
          acc0 = __builtin_amdgcn_mfma_f32_16x16x32_bf16(
                   __builtin_bit_cast(s8v, curA[i]), __builtin_bit_cast(s8v, b0), acc0, 0, 0, 0);
          acc1 = __builtin_amdgcn_mfma_f32_16x16x32_bf16(
                   __builtin_bit_cast(s8v, curA[i]), __builtin_bit_cast(s8v, b1), acc1, 0, 0, 0);
        }
#pragma unroll
        for (int i = 0; i < 8; ++i) curA[i] = nxtA[i];
      }
    }

    // ---- mode B: x phases (ks 48..95) ----
    if (!modeA) {
      auto consume12 = [&](int ksbase, int ldsbase) {
        const char* ab2 = ab + (size_t)ksbase * 4096;
        uint4 cA[6], nA[6];
#pragma unroll
        for (int i = 0; i < 6; ++i) cA[i] = *(const uint4*)(ab2 + (size_t)i * 4096);
#pragma unroll
        for (int i = 0; i < 6; ++i) nA[i] = *(const uint4*)(ab2 + (size_t)(6 + i) * 4096);
#pragma unroll
        for (int i = 0; i < 6; ++i) {
          uint4 b0 = *(const uint4*)(lds + ldsbase + (size_t)(i * 2 + 0) * 1024 + lane * 16);
          uint4 b1 = *(const uint4*)(lds + ldsbase + (size_t)(i * 2 + 1) * 1024 + lane * 16);
          acc0 = __builtin_amdgcn_mfma_f32_16x16x32_bf16(
                   __builtin_bit_cast(s8v, cA[i]), __builtin_bit_cast(s8v, b0), acc0, 0, 0, 0);
          acc1 = __builtin_amdgcn_mfma_f32_16x16x32_bf16(
                   __builtin_bit_cast(s8v, cA[i]), __builtin_bit_cast(s8v, b1), acc1, 0, 0, 0);
        }
#pragma unroll
        for (int i = 0; i < 6; ++i) {
          uint4 b0 = *(const uint4*)(lds + ldsbase + (size_t)((6 + i) * 2 + 0) * 1024 + lane * 16);
          uint4 b1 = *(const uint4*)(lds + ldsbase + (size_t)((6 + i) * 2 + 1) * 1024 + lane * 16);
          acc0 = __builtin_amdgcn_mfma_f32_16x16x32_bf16(
                   __builtin_bit_cast(s8v, nA[i]), __builtin_bit_cast(s8v, b0), acc0, 0, 0, 0);
          acc1 = __builtin_amdgcn_mfma_f32_16x16x32_bf16(
                   __builtin_bit_cast(s8v, nA[i]), __builtin_bit_cast(s8v, b1), acc1, 0, 0, 0);
        }
      };
      auto issue_chunk = [&](int q) {
        const size_t tc = ((size_t)t * 2 + ch) * 6144;
        const char* gb = xpb + (tc + (size_t)q * 1536) * 16;
        char* lb = lds + ((q & 1) ? LDS_X1 : LDS_X0) + wave * 1024;
#pragma unroll
        for (int i = 0; i < 6; ++i)
          gload_lds16(gb + (size_t)(i * 256 + tid) * 16, lb + i * 4096);
      };

      consume12(48, LDS_X0);
      __syncthreads();
      issue_chunk(2);
      consume12(60, LDS_X1);
      __syncthreads();
      issue_chunk(3);
      consume12(72, LDS_X0);
      __syncthreads();
      consume12(84, LDS_X1);
    }

    // ---- gate preactivations -> LDS ----
    {
      float* pre = (float*)(lds + LDS_X0);
#pragma unroll
      for (int reg = 0; reg < 4; ++reg) {
        int r = (lane >> 4) * 4 + reg;
        int cc = (lane & 15);
        pre[wave * 512 + r * 32 + cc]      = acc0[reg];
        pre[wave * 512 + r * 32 + 16 + cc] = acc1[reg];
      }
    }
    __syncthreads();

    // ---- pointwise gates, c/h update ----
    float hv0, hv1;
    {
      const float* pre = (const float*)(lds + LDS_X0);
      float gx0f = 0.f, gx0i = 0.f, gx0o = 0.f, gx0c = 0.f;
      float gx1f = 0.f, gx1i = 0.f, gx1o = 0.f, gx1c = 0.f;
      if (modeA) {
        gx0f = bf2f(gxr[0]); gx1f = bf2f(gxr[1]);
        gx0i = bf2f(gxr[2]); gx1i = bf2f(gxr[3]);
        gx0o = bf2f(gxr[4]); gx1o = bf2f(gxr[5]);
        gx0c = bf2f(gxr[6]); gx1c = bf2f(gxr[7]);
      }
      float pf = pre[0 * 512 + r0 * 32 + cl0] + vbf0 + gx0f;
      float pi = pre[1 * 512 + r0 * 32 + cl0] + vbi0 + gx0i;
      float po = pre[2 * 512 + r0 * 32 + cl0] + vbo0 + gx0o;
      float pc = pre[3 * 512 + r0 * 32 + cl0] + vbc0 + gx0c;
      float f = sigm(pf), ii = sigm(pi), o = sigm(po), cc = tanh_fast(pc);
      cst0 = f * cst0 + ii * cc;
      hv0 = o * tanh_fast(cst0);
      pf = pre[0 * 512 + (r0 + 8) * 32 + cl0] + vbf1 + gx1f;
      pi = pre[1 * 512 + (r0 + 8) * 32 + cl0] + vbi1 + gx1i;
      po = pre[2 * 512 + (r0 + 8) * 32 + cl0] + vbo1 + gx1o;
      pc = pre[3 * 512 + (r0 + 8) * 32 + cl0] + vbc1 + gx1c;
      f = sigm(pf); ii = sigm(pi); o = sigm(po); cc = tanh_fast(pc);
      cst1 = f * cst1 + ii * cc;
      hv1 = o * tanh_fast(cst1);
    }
    out[((size_t)t * 1536 + hr0) * 64 + cg0] = hv0;
    out[((size_t)t * 1536 + hr1) * 64 + cg0] = hv1;

    // ---- transpose h into LDS (X1 region, stride 24 for bank spread) ----
    {
      uint16_t* ht = (uint16_t*)(lds + LDS_X1);
      ht[cl0 * 24 + r0]     = f2bf(hv0);
      ht[cl0 * 24 + r0 + 8] = f2bf(hv1);
    }
    __syncthreads();

    // ---- coherent write of h slice to hstate[par^1] ----
    if (tid < 64) {
      int c_l = tid >> 1, half = tid & 1;
      uint4 v = *(const uint4*)(lds + LDS_X1 + ((size_t)c_l * 24 + half * 8) * 2);
      unsigned long long lo = *(unsigned long long*)&v.x;
      unsigned long long hi = *(unsigned long long*)&v.z;
      size_t off = (size_t)(par ^ 1) * 98304 + (size_t)(ch * 32 + c_l) * 1536 + rg * 16 + half * 8;
      unsigned long long* dp = (unsigned long long*)(hstate + off);
      __hip_atomic_store(dp,     lo, __ATOMIC_RELAXED, __HIP_MEMORY_SCOPE_SYSTEM);
      __hip_atomic_store(dp + 1, hi, __ATOMIC_RELAXED, __HIP_MEMORY_SCOPE_SYSTEM);
    }
    __syncthreads();   // drains the coherent stores before publishing

    // ---- publish: flag store (no RMW) ----
    if (tid == 0)
      __hip_atomic_store(flags + b, t + 1, __ATOMIC_RELAXED, __HIP_MEMORY_SCOPE_SYSTEM);
  }
}

// ============ host launcher ============
extern "C" void kernel_launch(void* const* d_in, const int* in_sizes, int n_in,
                              void* d_out, int out_size, void* d_ws, size_t ws_size,
                              hipStream_t stream) {
  (void)in_sizes; (void)n_in; (void)out_size;
  const float* x   = (const float*)d_in[0];
  const float* Wf  = (const float*)d_in[1];
  const float* bf_ = (const float*)d_in[2];
  const float* Wi  = (const float*)d_in[3];
  const float* bi_ = (const float*)d_in[4];
  const float* Wo  = (const float*)d_in[5];
  const float* bo_ = (const float*)d_in[6];
  const float* Wc  = (const float*)d_in[7];
  const float* bc_ = (const float*)d_in[8];
  const float* h0  = (const float*)d_in[9];
  const float* c0  = (const float*)d_in[10];

  if (ws_size < WS_B_NEEDED) return;   // diagnostic fail, not a crash
  const bool modeA = (ws_size >= WS_A_NEEDED);

  char* ws = (char*)d_ws;
  uint16_t* wp = (uint16_t*)(ws + WP_OFF);
  uint16_t* xp = (uint16_t*)(ws + XP_OFF);
  uint16_t* gx = modeA ? (uint16_t*)(ws + GX_OFF) : nullptr;
  uint16_t* hs = (uint16_t*)(ws + (modeA ? HS_A_OFF : HS_B_OFF));
  int* flags   = (int*)(ws + (modeA ? FL_A_OFF : FL_B_OFF));

  hipMemsetAsync(flags, 0, 1024, stream);
  pack_w<<<9216, 256, 0, stream>>>(Wf, Wi, Wo, Wc, wp);
  if (modeA) pack_xg<<<24576, 256, 0, stream>>>(x, xp);
  else       pack_x<<<24576, 256, 0, stream>>>(x, xp);
  pack_h0<<<384, 256, 0, stream>>>(h0, hs);
  if (modeA) gemm_gx<<<12288, 256, 0, stream>>>(wp, xp, gx);

  hipFuncSetAttribute(reinterpret_cast<const void*>(lstm_persist),
                      hipFuncAttributeMaxDynamicSharedMemorySize, LDS_TOTAL);
  lstm_persist<<<NWG, 256, LDS_TOTAL, stream>>>(bf_, bi_, bo_, bc_, c0,
                                                wp, xp, gx, hs, flags, (float*)d_out);
}

// Round 3
// 7996.627 us; speedup vs baseline: 1.4178x; 1.0429x over previous
//
#include <hip/hip_runtime.h>
#include <stdint.h>

#define TSTEPS 512
#define NWG 192

typedef short s8v __attribute__((ext_vector_type(8)));
typedef float f4v __attribute__((ext_vector_type(4)));
typedef unsigned long long ull;

// ---- workspace layout (bytes) ----
#define WP_BYTES  37748736ull               // packed weights bf16 (full K), fragment tiles
#define XP_BYTES 100663296ull               // packed x bf16 (GEMM B-granules)
#define GX_BYTES 402653184ull               // gx = Wx@x, bf16 [T][6144][64]
#define HS_BYTES    393216ull               // h state, 2 x 192 granules x 1KB
#define WP_OFF 0ull
#define XP_OFF 37748736ull
#define GX_OFF 138412032ull
#define HS_OFF (GX_OFF + GX_BYTES)
#define FL_OFF (HS_OFF + HS_BYTES)
#define WS_NEEDED (FL_OFF + 1024ull)        // ~516.6 MiB (proven available in round 2)

__device__ __forceinline__ uint16_t f2bf(float f) {
  union { float f; uint32_t u; } v; v.f = f;
  uint32_t u = v.u;
  return (uint16_t)((u + 0x7fffu + ((u >> 16) & 1u)) >> 16);
}
__device__ __forceinline__ float bf2f(uint32_t u) {
  union { uint32_t u; float f; } v; v.u = u << 16;
  return v.f;
}
__device__ __forceinline__ float sigm(float x) { return 1.0f / (1.0f + __expf(-x)); }
__device__ __forceinline__ float tanh_fast(float x) {
  float e = __expf(2.0f * x);
  return 1.0f - 2.0f / (e + 1.0f);
}
__device__ __forceinline__ void gload_lds16(const void* g, void* l) {
  typedef __attribute__((address_space(1))) uint32_t g32;
  typedef __attribute__((address_space(3))) uint32_t l32;
  __builtin_amdgcn_global_load_lds((g32*)g, (l32*)l, 16, 0, 0);
}

// ============ prep kernels ============

// Pack W{f,i,o,c} fp32 [1536][3072] -> bf16 fragment tiles (full K).
// tile id = ((rg*96 + ks)*4 + g); lane l holds 16B =
// W_g[rg*16 + (l&15)][ks*32 + (l>>4)*8 + j], j=0..7
__global__ void pack_w(const float* __restrict__ Wf, const float* __restrict__ Wi,
                       const float* __restrict__ Wo, const float* __restrict__ Wc,
                       uint16_t* __restrict__ wp) {
  int tile = blockIdx.x * 4 + (threadIdx.x >> 6);
  int lane = threadIdx.x & 63;
  int g  = tile & 3;
  int ks = (tile >> 2) % 96;
  int rg = tile / 384;
  const float* W = (g == 0) ? Wf : (g == 1) ? Wi : (g == 2) ? Wo : Wc;
  int hr = rg * 16 + (lane & 15);
  int kk = ks * 32 + (lane >> 4) * 8;
  const float* src = W + (size_t)hr * 3072 + kk;
  uint32_t w[4];
#pragma unroll
  for (int j = 0; j < 4; ++j) {
    uint32_t lo = f2bf(src[2 * j]);
    uint32_t hi = f2bf(src[2 * j + 1]);
    w[j] = lo | (hi << 16);
  }
  *(uint4*)((char*)wp + (size_t)tile * 1024 + (size_t)lane * 16) = make_uint4(w[0], w[1], w[2], w[3]);
}

// Pack x as GEMM B-fragment granules. granule gi = n16*48 + ks;
// lane l: col n = n16*16 + (l&15) -> t=n>>6, b=n&63; k-row i = ks*32+(l>>4)*8+j
__global__ void pack_xg(const float* __restrict__ x, uint16_t* __restrict__ xg) {
  size_t gi4 = (size_t)blockIdx.x * 4 + (threadIdx.x >> 6);  // granule, < 98304
  int lane = threadIdx.x & 63;
  int n16 = (int)(gi4 / 48);
  int ks  = (int)(gi4 % 48);
  int n = n16 * 16 + (lane & 15);
  int t = n >> 6, bb = n & 63;
  int i0 = ks * 32 + (lane >> 4) * 8;
  const float* src = x + ((size_t)t * 1536 + i0) * 64 + bb;
  uint32_t w[4];
#pragma unroll
  for (int j = 0; j < 4; ++j) {
    uint32_t lo = f2bf(src[(size_t)(2 * j) * 64]);
    uint32_t hi = f2bf(src[(size_t)(2 * j + 1) * 64]);
    w[j] = lo | (hi << 16);
  }
  *(uint4*)((char*)xg + gi4 * 1024 + (size_t)lane * 16) = make_uint4(w[0], w[1], w[2], w[3]);
}

// h0 fp32 [1536][64] -> hstate[par=0] in granule layout:
// granule gr = (ch*48 + ks)*2 + cf; lane l holds 16B = bf16
// h[k = ks*32+(l>>4)*8+j][col = ch*32+cf*16+(l&15)], j=0..7
__global__ void pack_h0(const float* __restrict__ h0, uint16_t* __restrict__ hs) {
  int tg = blockIdx.x * 256 + threadIdx.x;    // < 12288
  int lane = tg & 63, gr = tg >> 6;           // gr < 192
  int cf = gr & 1, r2 = gr >> 1;
  int ks = r2 % 48, ch = r2 / 48;
  int col = ch * 32 + cf * 16 + (lane & 15);
  int k0 = ks * 32 + (lane >> 4) * 8;
  const float* src = h0 + (size_t)k0 * 64 + col;
  uint32_t w[4];
#pragma unroll
  for (int j = 0; j < 4; ++j) {
    uint32_t lo = f2bf(src[(size_t)(2 * j) * 64]);
    uint32_t hi = f2bf(src[(size_t)(2 * j + 1) * 64]);
    w[j] = lo | (hi << 16);
  }
  *(uint4*)((char*)hs + (size_t)gr * 1024 + (size_t)lane * 16) = make_uint4(w[0], w[1], w[2], w[3]);
}

// ============ gx = Wx @ X  (M=6144, N=32768, K=1536) ============
__global__ __launch_bounds__(256) void gemm_gx(const uint16_t* __restrict__ wp,
                                               const uint16_t* __restrict__ xg,
                                               uint16_t* __restrict__ gxp) {
  __shared__ char lds[32768];
  const int tid = threadIdx.x;
  const int lane = tid & 63, wave = tid >> 6;
  const int bid = blockIdx.x;
  const int mb = bid >> 8;                // 0..47
  const int nb = bid & 255;               // 0..255
  const int wm = wave >> 1, wn = wave & 1;

  const char* wpb = (const char*)wp;
  const char* xgb = (const char*)xg;
  const int g   = (mb * 8) / 96;
  const int rgb = (mb * 8) % 96;

  auto stage = [&](int ks, int buf) {
    char* Ad = lds + buf * 16384 + wave * 1024;
    char* Bd = lds + buf * 16384 + 8192 + wave * 1024;
#pragma unroll
    for (int p = 0; p < 2; ++p) {
      int l = wave + p * 4;
      size_t atile = ((size_t)(rgb + l) * 96 + 48 + ks) * 4 + g;
      gload_lds16(wpb + atile * 1024 + (size_t)lane * 16, Ad + p * 4096);
      size_t btile = (size_t)(nb * 8 + l) * 48 + ks;
      gload_lds16(xgb + btile * 1024 + (size_t)lane * 16, Bd + p * 4096);
    }
  };

  stage(0, 0);
  __syncthreads();

  f4v acc[4][4];
#pragma unroll
  for (int i = 0; i < 4; ++i)
#pragma unroll
    for (int j = 0; j < 4; ++j) acc[i][j] = f4v{0.f, 0.f, 0.f, 0.f};

  for (int ks = 0; ks < 48; ++ks) {
    int buf = ks & 1;
    if (ks < 47) stage(ks + 1, buf ^ 1);
    const char* Ab = lds + buf * 16384 + (size_t)(wm * 4) * 1024;
    const char* Bb = lds + buf * 16384 + 8192 + (size_t)(wn * 4) * 1024;
    uint4 af[4], bfr[4];
#pragma unroll
    for (int i = 0; i < 4; ++i) af[i]  = *(const uint4*)(Ab + (size_t)i * 1024 + (size_t)lane * 16);
#pragma unroll
    for (int j = 0; j < 4; ++j) bfr[j] = *(const uint4*)(Bb + (size_t)j * 1024 + (size_t)lane * 16);
#pragma unroll
    for (int i = 0; i < 4; ++i)
#pragma unroll
      for (int j = 0; j < 4; ++j)
        acc[i][j] = __builtin_amdgcn_mfma_f32_16x16x32_bf16(
            __builtin_bit_cast(s8v, af[i]), __builtin_bit_cast(s8v, bfr[j]), acc[i][j], 0, 0, 0);
    __syncthreads();
  }

#pragma unroll
  for (int i = 0; i < 4; ++i) {
    int m = (mb * 8 + wm * 4 + i) * 16 + (lane >> 4) * 4;
#pragma unroll
    for (int j = 0; j < 4; ++j) {
      int n = (nb * 8 + wn * 4 + j) * 16 + (lane & 15);
      int tt = n >> 6, bb = n & 63;
#pragma unroll
      for (int r = 0; r < 4; ++r)
        gxp[((size_t)tt * 6144 + m + r) * 64 + bb] = f2bf(acc[i][j][r]);
    }
  }
}

// ============ persistent LSTM kernel ============
// 192 blocks x 256 threads. block b: ch = b/96, rg = b%96 (rows rg*16..+15,
// cols ch*32..+31). K-split: wave w handles ks = w*12..w*12+11 for ALL 4
// gates. Weights live entirely in VGPRs (48 tiles = 192 regs/lane). B (h)
// granules read with NORMAL cached loads after an agent-scope acquire fence
// (buffer_inv); producers store h system-scope (straight to LLC) + waitcnt
// + flag. LDS only for partial-sum reduction (32KB) + h transpose (1.5KB).
__global__ __launch_bounds__(256, 1) void lstm_persist(
    const float* __restrict__ bfp, const float* __restrict__ bip,
    const float* __restrict__ bop, const float* __restrict__ bcp,
    const float* __restrict__ c0p,
    const uint16_t* __restrict__ wp, const uint16_t* __restrict__ gxp,
    uint16_t* __restrict__ hstate, int* __restrict__ flags,
    float* __restrict__ out)
{
  __shared__ __align__(16) char smem[32768 + 1536];   // partials | ht
  uint16_t* ht = (uint16_t*)(smem + 32768);           // [col][24] stride-24 bf16
  const int tid = threadIdx.x;
  const int wave = tid >> 6, lane = tid & 63;
  const int b = blockIdx.x;
  const int ch = b / 96, rg = b % 96;

  // epilogue thread mapping: c = tid&31 (local col), rows rr and rr+8
  const int c = tid & 31, rr = tid >> 5;              // rr in 0..7
  const int hr0 = rg * 16 + rr, hr1 = hr0 + 8;
  const int cg = ch * 32 + c;
  const int cfE = c >> 4, c15e = c & 15;
  // partial-read float index for (g=0, w=0, elem0); strides: g=+512, w=+2048, elem1=+128
  const int rbase = ((cfE * 64) + (rr >> 2) * 16 + c15e) * 4 + (rr & 3);

  float cst0 = c0p[(size_t)hr0 * 64 + cg];
  float cst1 = c0p[(size_t)hr1 * 64 + cg];
  const float vb0[4] = {bfp[hr0], bip[hr0], bop[hr0], bcp[hr0]};
  const float vb1[4] = {bfp[hr1], bip[hr1], bop[hr1], bcp[hr1]};

  // ---- load ALL recurrent weights into registers: Ar[q][g], 48 x 16B ----
  uint4 Ar[12][4];
  {
    const char* wpb = (const char*)wp;
#pragma unroll
    for (int q = 0; q < 12; ++q)
#pragma unroll
      for (int g = 0; g < 4; ++g) {
        size_t tile = ((size_t)rg * 96 + wave * 12 + q) * 4 + g;
        Ar[q][g] = *(const uint4*)(wpb + tile * 1024 + (size_t)lane * 16);
      }
  }

  const char* hsb = (const char*)hstate;

  for (int t = 0; t < TSTEPS; ++t) {
    const int par = t & 1;

    // ---- gx prefetch (immutable data; issued before the wait) ----
    uint32_t gxr[8];
    {
      const uint16_t* gbase = gxp + ((size_t)t * 6144 + hr0) * 64 + cg;
#pragma unroll
      for (int g = 0; g < 4; ++g) {
#pragma unroll
        for (int s = 0; s < 2; ++s)
          gxr[g * 2 + s] = gbase[((size_t)g * 1536 + s * 8) * 64];
      }
    }

    // ---- poll flags (all waves independently; sc-bypass loads) ----
    if (t > 0) {
      const int need = t;
      for (;;) {
        int ok = 1;
        if (lane < 48) {
          const ull* fp = (const ull*)(flags + lane * 4);
          ull a = __hip_atomic_load(fp,     __ATOMIC_RELAXED, __HIP_MEMORY_SCOPE_SYSTEM);
          ull d = __hip_atomic_load(fp + 1, __ATOMIC_RELAXED, __HIP_MEMORY_SCOPE_SYSTEM);
          int f0 = (int)(unsigned)a, f1 = (int)(a >> 32);
          int f2 = (int)(unsigned)d, f3 = (int)(d >> 32);
          ok = (f0 >= need) & (f1 >= need) & (f2 >= need) & (f3 >= need);
        }
        if (__all(ok)) break;
        __builtin_amdgcn_s_sleep(1);
      }
    }
    // acquire: invalidate L1/L2 so cached h loads see the LLC data
    __builtin_amdgcn_fence(__ATOMIC_ACQUIRE, "agent");

    // ---- B granules: normal cached loads (L2-shared across blocks) ----
    uint4 Bg[12][2];
    {
      const char* base = hsb + (((size_t)(par * 2 + ch) * 48 + wave * 12) * 2) * 1024
                             + (size_t)lane * 16;
#pragma unroll
      for (int q = 0; q < 12; ++q) {
#pragma unroll
        for (int cf = 0; cf < 2; ++cf)
          Bg[q][cf] = *(const uint4*)(base + (size_t)q * 2048 + (size_t)cf * 1024);
      }
    }

    // ---- MFMA: 96 per wave, all operands in registers ----
    f4v acc[4][2];
#pragma unroll
    for (int g = 0; g < 4; ++g)
#pragma unroll
      for (int cf = 0; cf < 2; ++cf) acc[g][cf] = f4v{0.f, 0.f, 0.f, 0.f};
#pragma unroll
    for (int q = 0; q < 12; ++q)
#pragma unroll
      for (int g = 0; g < 4; ++g)
#pragma unroll
        for (int cf = 0; cf < 2; ++cf)
          acc[g][cf] = __builtin_amdgcn_mfma_f32_16x16x32_bf16(
              __builtin_bit_cast(s8v, Ar[q][g]), __builtin_bit_cast(s8v, Bg[q][cf]),
              acc[g][cf], 0, 0, 0);

    // ---- write partials to LDS: [w][g][cf][lane] x 16B ----
#pragma unroll
    for (int g = 0; g < 4; ++g)
#pragma unroll
      for (int cf = 0; cf < 2; ++cf)
        *(uint4*)(smem + (((size_t)wave * 8 + g * 2 + cf) * 64 + lane) * 16)
            = __builtin_bit_cast(uint4, acc[g][cf]);
    __syncthreads();   // reduction barrier

    // ---- reduce 4 waves + gates epilogue ----
    float hv0, hv1;
    {
      const float* P = (const float*)smem;
      float s0[4], s1[4];
#pragma unroll
      for (int g = 0; g < 4; ++g) {
        int i0 = rbase + g * 512;
        s0[g] = P[i0] + P[i0 + 2048] + P[i0 + 4096] + P[i0 + 6144];
        int i1 = i0 + 128;
        s1[g] = P[i1] + P[i1 + 2048] + P[i1 + 4096] + P[i1 + 6144];
      }
      float pf = s0[0] + vb0[0] + bf2f(gxr[0]);
      float pi = s0[1] + vb0[1] + bf2f(gxr[2]);
      float po = s0[2] + vb0[2] + bf2f(gxr[4]);
      float pc = s0[3] + vb0[3] + bf2f(gxr[6]);
      float f = sigm(pf), ii = sigm(pi), o = sigm(po), cc = tanh_fast(pc);
      cst0 = f * cst0 + ii * cc;
      hv0 = o * tanh_fast(cst0);
      pf = s1[0] + vb1[0] + bf2f(gxr[1]);
      pi = s1[1] + vb1[1] + bf2f(gxr[3]);
      po = s1[2] + vb1[2] + bf2f(gxr[5]);
      pc = s1[3] + vb1[3] + bf2f(gxr[7]);
      f = sigm(pf); ii = sigm(pi); o = sigm(po); cc = tanh_fast(pc);
      cst1 = f * cst1 + ii * cc;
      hv1 = o * tanh_fast(cst1);
    }
    out[((size_t)t * 1536 + hr0) * 64 + cg] = hv0;
    out[((size_t)t * 1536 + hr1) * 64 + cg] = hv1;

    // ---- transpose h into LDS (stride-24 bf16) ----
    ht[c * 24 + rr]     = f2bf(hv0);
    ht[c * 24 + rr + 8] = f2bf(hv1);
    __syncthreads();   // barrier X: partials consumed, ht complete

    // ---- wave 0: publish h granule-halves (system scope) + flag ----
    if (wave == 0) {
      int cf2 = lane >> 5, hh = (lane >> 4) & 1, c15 = lane & 15;
      uint4 v = *(const uint4*)(ht + (cf2 * 16 + c15) * 24 + hh * 8);
      size_t gidx = ((size_t)((par ^ 1) * 2 + ch) * 48 + (rg >> 1)) * 2 + cf2;
      int l_in = ((rg & 1) * 2 + hh) * 16 + c15;
      ull* dp = (ull*)((char*)hstate + gidx * 1024 + (size_t)l_in * 16);
      __hip_atomic_store(dp,     *(ull*)&v.x, __ATOMIC_RELAXED, __HIP_MEMORY_SCOPE_SYSTEM);
      __hip_atomic_store(dp + 1, *(ull*)&v.z, __ATOMIC_RELAXED, __HIP_MEMORY_SCOPE_SYSTEM);
      asm volatile("s_waitcnt vmcnt(0)" ::: "memory");   // h at LLC before flag
      if (lane == 0)
        __hip_atomic_store(flags + b, t + 1, __ATOMIC_RELAXED, __HIP_MEMORY_SCOPE_SYSTEM);
    }
  }
}

// ============ host launcher ============
extern "C" void kernel_launch(void* const* d_in, const int* in_sizes, int n_in,
                              void* d_out, int out_size, void* d_ws, size_t ws_size,
                              hipStream_t stream) {
  (void)in_sizes; (void)n_in; (void)out_size;
  const float* x   = (const float*)d_in[0];
  const float* Wf  = (const float*)d_in[1];
  const float* bf_ = (const float*)d_in[2];
  const float* Wi  = (const float*)d_in[3];
  const float* bi_ = (const float*)d_in[4];
  const float* Wo  = (const float*)d_in[5];
  const float* bo_ = (const float*)d_in[6];
  const float* Wc  = (const float*)d_in[7];
  const float* bc_ = (const float*)d_in[8];
  const float* h0  = (const float*)d_in[9];
  const float* c0  = (const float*)d_in[10];

  if (ws_size < WS_NEEDED) return;   // diagnostic fail, not a crash

  char* ws = (char*)d_ws;
  uint16_t* wp = (uint16_t*)(ws + WP_OFF);
  uint16_t* xp = (uint16_t*)(ws + XP_OFF);
  uint16_t* gx = (uint16_t*)(ws + GX_OFF);
  uint16_t* hs = (uint16_t*)(ws + HS_OFF);
  int* flags   = (int*)(ws + FL_OFF);

  hipMemsetAsync(flags, 0, 1024, stream);
  pack_w<<<9216, 256, 0, stream>>>(Wf, Wi, Wo, Wc, wp);
  pack_xg<<<24576, 256, 0, stream>>>(x, xp);
  pack_h0<<<48, 256, 0, stream>>>(h0, hs);
  gemm_gx<<<12288, 256, 0, stream>>>(wp, xp, gx);

  lstm_persist<<<NWG, 256, 0, stream>>>(bf_, bi_, bo_, bc_, c0,
                                        wp, gx, hs, flags, (float*)d_out);
}

// Round 5
// 5070.944 us; speedup vs baseline: 2.2359x; 1.5770x over previous
//
#include <hip/hip_runtime.h>
#include <stdint.h>

#define TSTEPS 512
#define NWG 192

typedef short s8v __attribute__((ext_vector_type(8)));
typedef float f4v __attribute__((ext_vector_type(4)));
typedef unsigned long long ull;

// ---- workspace layout (bytes) ----
#define WP_BYTES  37748736ull               // packed weights bf16 (full K), fragment tiles
#define XP_BYTES 100663296ull               // packed x bf16 (GEMM B-granules)
#define GX_BYTES 402653184ull               // gx = Wx@x, bf16 [T][6144][64]
#define HS_BYTES    393216ull               // h state, 2 x 192 granules x 1KB
#define WP_OFF 0ull
#define XP_OFF 37748736ull
#define GX_OFF 138412032ull
#define HS_OFF (GX_OFF + GX_BYTES)
#define FL_OFF (HS_OFF + HS_BYTES)
#define WS_NEEDED (FL_OFF + 1024ull)        // ~516.6 MiB (proven available)

__device__ __forceinline__ uint16_t f2bf(float f) {
  union { float f; uint32_t u; } v; v.f = f;
  uint32_t u = v.u;
  return (uint16_t)((u + 0x7fffu + ((u >> 16) & 1u)) >> 16);
}
__device__ __forceinline__ float bf2f(uint32_t u) {
  union { uint32_t u; float f; } v; v.u = u << 16;
  return v.f;
}
__device__ __forceinline__ float sigm(float x) { return 1.0f / (1.0f + __expf(-x)); }
__device__ __forceinline__ float tanh_fast(float x) {
  float e = __expf(2.0f * x);
  return 1.0f - 2.0f / (e + 1.0f);
}
__device__ __forceinline__ void gload_lds16(const void* g, void* l) {
  typedef __attribute__((address_space(1))) uint32_t g32;
  typedef __attribute__((address_space(3))) uint32_t l32;
  __builtin_amdgcn_global_load_lds((g32*)g, (l32*)l, 16, 0, 0);
}

// ============ prep kernels ============

// Pack W{f,i,o,c} fp32 [1536][3072] -> bf16 fragment tiles (full K).
// tile id = ((rg*96 + ks)*4 + g); lane l holds 16B =
// W_g[rg*16 + (l&15)][ks*32 + (l>>4)*8 + j], j=0..7
__global__ void pack_w(const float* __restrict__ Wf, const float* __restrict__ Wi,
                       const float* __restrict__ Wo, const float* __restrict__ Wc,
                       uint16_t* __restrict__ wp) {
  int tile = blockIdx.x * 4 + (threadIdx.x >> 6);
  int lane = threadIdx.x & 63;
  int g  = tile & 3;
  int ks = (tile >> 2) % 96;
  int rg = tile / 384;
  const float* W = (g == 0) ? Wf : (g == 1) ? Wi : (g == 2) ? Wo : Wc;
  int hr = rg * 16 + (lane & 15);
  int kk = ks * 32 + (lane >> 4) * 8;
  const float* src = W + (size_t)hr * 3072 + kk;
  uint32_t w[4];
#pragma unroll
  for (int j = 0; j < 4; ++j) {
    uint32_t lo = f2bf(src[2 * j]);
    uint32_t hi = f2bf(src[2 * j + 1]);
    w[j] = lo | (hi << 16);
  }
  *(uint4*)((char*)wp + (size_t)tile * 1024 + (size_t)lane * 16) = make_uint4(w[0], w[1], w[2], w[3]);
}

// Pack x as GEMM B-fragment granules. granule gi = n16*48 + ks;
// lane l: col n = n16*16 + (l&15) -> t=n>>6, b=n&63; k-row i = ks*32+(l>>4)*8+j
__global__ void pack_xg(const float* __restrict__ x, uint16_t* __restrict__ xg) {
  size_t gi4 = (size_t)blockIdx.x * 4 + (threadIdx.x >> 6);  // granule, < 98304
  int lane = threadIdx.x & 63;
  int n16 = (int)(gi4 / 48);
  int ks  = (int)(gi4 % 48);
  int n = n16 * 16 + (lane & 15);
  int t = n >> 6, bb = n & 63;
  int i0 = ks * 32 + (lane >> 4) * 8;
  const float* src = x + ((size_t)t * 1536 + i0) * 64 + bb;
  uint32_t w[4];
#pragma unroll
  for (int j = 0; j < 4; ++j) {
    uint32_t lo = f2bf(src[(size_t)(2 * j) * 64]);
    uint32_t hi = f2bf(src[(size_t)(2 * j + 1) * 64]);
    w[j] = lo | (hi << 16);
  }
  *(uint4*)((char*)xg + gi4 * 1024 + (size_t)lane * 16) = make_uint4(w[0], w[1], w[2], w[3]);
}

// h0 fp32 [1536][64] -> hstate[par=0] in granule layout:
// granule gr = (ch*48 + ks)*2 + cf; lane l holds 16B = bf16
// h[k = ks*32+(l>>4)*8+j][col = ch*32+cf*16+(l&15)], j=0..7
__global__ void pack_h0(const float* __restrict__ h0, uint16_t* __restrict__ hs) {
  int tg = blockIdx.x * 256 + threadIdx.x;    // < 12288
  int lane = tg & 63, gr = tg >> 6;           // gr < 192
  int cf = gr & 1, r2 = gr >> 1;
  int ks = r2 % 48, ch = r2 / 48;
  int col = ch * 32 + cf * 16 + (lane & 15);
  int k0 = ks * 32 + (lane >> 4) * 8;
  const float* src = h0 + (size_t)k0 * 64 + col;
  uint32_t w[4];
#pragma unroll
  for (int j = 0; j < 4; ++j) {
    uint32_t lo = f2bf(src[(size_t)(2 * j) * 64]);
    uint32_t hi = f2bf(src[(size_t)(2 * j + 1) * 64]);
    w[j] = lo | (hi << 16);
  }
  *(uint4*)((char*)hs + (size_t)gr * 1024 + (size_t)lane * 16) = make_uint4(w[0], w[1], w[2], w[3]);
}

// ============ gx = Wx @ X  (M=6144, N=32768, K=1536) ============
__global__ __launch_bounds__(256) void gemm_gx(const uint16_t* __restrict__ wp,
                                               const uint16_t* __restrict__ xg,
                                               uint16_t* __restrict__ gxp) {
  __shared__ char lds[32768];
  const int tid = threadIdx.x;
  const int lane = tid & 63, wave = tid >> 6;
  const int bid = blockIdx.x;
  const int mb = bid >> 8;                // 0..47
  const int nb = bid & 255;               // 0..255
  const int wm = wave >> 1, wn = wave & 1;

  const char* wpb = (const char*)wp;
  const char* xgb = (const char*)xg;
  const int g   = (mb * 8) / 96;
  const int rgb = (mb * 8) % 96;

  auto stage = [&](int ks, int buf) {
    char* Ad = lds + buf * 16384 + wave * 1024;
    char* Bd = lds + buf * 16384 + 8192 + wave * 1024;
#pragma unroll
    for (int p = 0; p < 2; ++p) {
      int l = wave + p * 4;
      size_t atile = ((size_t)(rgb + l) * 96 + 48 + ks) * 4 + g;
      gload_lds16(wpb + atile * 1024 + (size_t)lane * 16, Ad + p * 4096);
      size_t btile = (size_t)(nb * 8 + l) * 48 + ks;
      gload_lds16(xgb + btile * 1024 + (size_t)lane * 16, Bd + p * 4096);
    }
  };

  stage(0, 0);
  __syncthreads();

  f4v acc[4][4];
#pragma unroll
  for (int i = 0; i < 4; ++i)
#pragma unroll
    for (int j = 0; j < 4; ++j) acc[i][j] = f4v{0.f, 0.f, 0.f, 0.f};

  for (int ks = 0; ks < 48; ++ks) {
    int buf = ks & 1;
    if (ks < 47) stage(ks + 1, buf ^ 1);
    const char* Ab = lds + buf * 16384 + (size_t)(wm * 4) * 1024;
    const char* Bb = lds + buf * 16384 + 8192 + (size_t)(wn * 4) * 1024;
    uint4 af[4], bfr[4];
#pragma unroll
    for (int i = 0; i < 4; ++i) af[i]  = *(const uint4*)(Ab + (size_t)i * 1024 + (size_t)lane * 16);
#pragma unroll
    for (int j = 0; j < 4; ++j) bfr[j] = *(const uint4*)(Bb + (size_t)j * 1024 + (size_t)lane * 16);
#pragma unroll
    for (int i = 0; i < 4; ++i)
#pragma unroll
      for (int j = 0; j < 4; ++j)
        acc[i][j] = __builtin_amdgcn_mfma_f32_16x16x32_bf16(
            __builtin_bit_cast(s8v, af[i]), __builtin_bit_cast(s8v, bfr[j]), acc[i][j], 0, 0, 0);
    __syncthreads();
  }

#pragma unroll
  for (int i = 0; i < 4; ++i) {
    int m = (mb * 8 + wm * 4 + i) * 16 + (lane >> 4) * 4;
#pragma unroll
    for (int j = 0; j < 4; ++j) {
      int n = (nb * 8 + wn * 4 + j) * 16 + (lane & 15);
      int tt = n >> 6, bb = n & 63;
#pragma unroll
      for (int r = 0; r < 4; ++r)
        gxp[((size_t)tt * 6144 + m + r) * 64 + bb] = f2bf(acc[i][j][r]);
    }
  }
}

// ============ persistent LSTM kernel ============
// 192 blocks x 256 threads. block b: ch = b/96, rg = b%96 (rows rg*16..+15,
// cols ch*32..+31). K-split: wave w handles ks = w*12..w*12+11 for ALL 4
// gates. Weights loaded ONCE before the t-loop; wp/hstate are deliberately
// NOT __restrict__ so the in-loop hstate stores may-alias wp — sinking the
// weight loads into the loop is then illegal and the 192 values stay
// register-resident (unified VGPR/AGPR file, 512 regs @ 1 wave/SIMD).
// h granules read with system-scope relaxed 8B loads (LLC-direct, no
// fence/inv — L2 stays warm for gx). Barrier: per-column-half 96-flag poll.
__global__ __launch_bounds__(256, 1) void lstm_persist(
    const float* __restrict__ bfp, const float* __restrict__ bip,
    const float* __restrict__ bop, const float* __restrict__ bcp,
    const float* __restrict__ c0p,
    const uint16_t* wp,              // NOT restrict: may-alias hstate (blocks load-sinking)
    const uint16_t* __restrict__ gxp,
    uint16_t* hstate,                // NOT restrict
    int* __restrict__ flags,
    float* __restrict__ out)
{
  __shared__ __align__(16) char smem[32768 + 1536];   // partials | ht
  uint16_t* ht = (uint16_t*)(smem + 32768);           // [col][24] stride-24 bf16
  const int tid = threadIdx.x;
  const int wave = tid >> 6, lane = tid & 63;
  const int b = blockIdx.x;
  const int ch = b / 96, rg = b % 96;

  // epilogue thread mapping: c = tid&31 (local col), rows rr and rr+8
  const int c = tid & 31, rr = tid >> 5;              // rr in 0..7
  const int hr0 = rg * 16 + rr, hr1 = hr0 + 8;
  const int cg = ch * 32 + c;
  const int cfE = c >> 4, c15e = c & 15;
  const int rbase = ((cfE * 64) + (rr >> 2) * 16 + c15e) * 4 + (rr & 3);

  float cst0 = c0p[(size_t)hr0 * 64 + cg];
  float cst1 = c0p[(size_t)hr1 * 64 + cg];
  const float vb0[4] = {bfp[hr0], bip[hr0], bop[hr0], bcp[hr0]};
  const float vb1[4] = {bfp[hr1], bip[hr1], bop[hr1], bcp[hr1]};

  // ---- load ALL recurrent weights into registers (held across t-loop) ----
  uint4 Ar[12][4];
  {
    const char* wpb = (const char*)wp;
#pragma unroll
    for (int q = 0; q < 12; ++q)
#pragma unroll
      for (int g = 0; g < 4; ++g) {
        size_t tile = ((size_t)rg * 96 + wave * 12 + q) * 4 + g;
        Ar[q][g] = *(const uint4*)(wpb + tile * 1024 + (size_t)lane * 16);
      }
  }

  const char* hsb = (const char*)hstate;

  for (int t = 0; t < TSTEPS; ++t) {
    const int par = t & 1;

    // ---- gx prefetch (immutable; issued before the wait, overlaps poll) ----
    uint32_t gxr[8];
    {
      const uint16_t* gbase = gxp + ((size_t)t * 6144 + hr0) * 64 + cg;
#pragma unroll
      for (int g = 0; g < 4; ++g) {
#pragma unroll
        for (int s = 0; s < 2; ++s)
          gxr[g * 2 + s] = gbase[((size_t)g * 1536 + s * 8) * 64];
      }
    }

    // ---- wave0 polls the 96 same-ch flags; barrier releases the block ----
    if (t > 0 && wave == 0) {
      const int need = t;
      const ull* fb = (const ull*)(flags + ch * 96);
      for (;;) {
        int ok = 1;
        if (lane < 48) {
          ull a = __hip_atomic_load(fb + lane, __ATOMIC_RELAXED, __HIP_MEMORY_SCOPE_SYSTEM);
          int f0 = (int)(unsigned)a, f1 = (int)(a >> 32);
          ok = (f0 >= need) & (f1 >= need);
        }
        if (__all(ok)) break;
        __builtin_amdgcn_s_sleep(1);
      }
    }
    __syncthreads();   // release: h for step t is at LLC

    // ---- B granules: system-scope (LLC-direct) loads into registers ----
    uint4 Bg[12][2];
    {
      const char* base = hsb + (((size_t)(par * 2 + ch) * 48 + wave * 12) * 2) * 1024
                             + (size_t)lane * 16;
#pragma unroll
      for (int q = 0; q < 12; ++q) {
#pragma unroll
        for (int cf = 0; cf < 2; ++cf) {
          const ull* p = (const ull*)(base + (size_t)q * 2048 + (size_t)cf * 1024);
          ull lo = __hip_atomic_load(p,     __ATOMIC_RELAXED, __HIP_MEMORY_SCOPE_SYSTEM);
          ull hi = __hip_atomic_load(p + 1, __ATOMIC_RELAXED, __HIP_MEMORY_SCOPE_SYSTEM);
          uint4 v;
          *(ull*)&v.x = lo;
          *(ull*)&v.z = hi;
          Bg[q][cf] = v;
        }
      }
    }

    // ---- MFMA: 96 per wave, all operands in registers ----
    f4v acc[4][2];
#pragma unroll
    for (int g = 0; g < 4; ++g)
#pragma unroll
      for (int cf = 0; cf < 2; ++cf) acc[g][cf] = f4v{0.f, 0.f, 0.f, 0.f};
#pragma unroll
    for (int q = 0; q < 12; ++q)
#pragma unroll
      for (int g = 0; g < 4; ++g)
#pragma unroll
        for (int cf = 0; cf < 2; ++cf)
          acc[g][cf] = __builtin_amdgcn_mfma_f32_16x16x32_bf16(
              __builtin_bit_cast(s8v, Ar[q][g]), __builtin_bit_cast(s8v, Bg[q][cf]),
              acc[g][cf], 0, 0, 0);

    // ---- write partials to LDS: [w][g][cf][lane] x 16B ----
#pragma unroll
    for (int g = 0; g < 4; ++g)
#pragma unroll
      for (int cf = 0; cf < 2; ++cf)
        *(uint4*)(smem + (((size_t)wave * 8 + g * 2 + cf) * 64 + lane) * 16)
            = __builtin_bit_cast(uint4, acc[g][cf]);
    __syncthreads();   // reduction barrier

    // ---- reduce 4 waves + gates epilogue ----
    float hv0, hv1;
    {
      const float* P = (const float*)smem;
      float s0[4], s1[4];
#pragma unroll
      for (int g = 0; g < 4; ++g) {
        int i0 = rbase + g * 512;
        s0[g] = P[i0] + P[i0 + 2048] + P[i0 + 4096] + P[i0 + 6144];
        int i1 = i0 + 128;
        s1[g] = P[i1] + P[i1 + 2048] + P[i1 + 4096] + P[i1 + 6144];
      }
      float pf = s0[0] + vb0[0] + bf2f(gxr[0]);
      float pi = s0[1] + vb0[1] + bf2f(gxr[2]);
      float po = s0[2] + vb0[2] + bf2f(gxr[4]);
      float pc = s0[3] + vb0[3] + bf2f(gxr[6]);
      float f = sigm(pf), ii = sigm(pi), o = sigm(po), cc = tanh_fast(pc);
      cst0 = f * cst0 + ii * cc;
      hv0 = o * tanh_fast(cst0);
      pf = s1[0] + vb1[0] + bf2f(gxr[1]);
      pi = s1[1] + vb1[1] + bf2f(gxr[3]);
      po = s1[2] + vb1[2] + bf2f(gxr[5]);
      pc = s1[3] + vb1[3] + bf2f(gxr[7]);
      f = sigm(pf); ii = sigm(pi); o = sigm(po); cc = tanh_fast(pc);
      cst1 = f * cst1 + ii * cc;
      hv1 = o * tanh_fast(cst1);
    }

    // ---- transpose h into LDS (stride-24 bf16) ----
    ht[c * 24 + rr]     = f2bf(hv0);
    ht[c * 24 + rr + 8] = f2bf(hv1);
    __syncthreads();   // partials consumed, ht complete

    // ---- wave 0: publish h granule-halves (system scope) + flag ----
    // out stores are issued AFTER the flag so vmcnt(0) drains only h stores.
    if (wave == 0) {
      int cf2 = lane >> 5, hh = (lane >> 4) & 1, c15 = lane & 15;
      uint4 v = *(const uint4*)(ht + (cf2 * 16 + c15) * 24 + hh * 8);
      size_t gidx = ((size_t)((par ^ 1) * 2 + ch) * 48 + (rg >> 1)) * 2 + cf2;
      int l_in = ((rg & 1) * 2 + hh) * 16 + c15;
      ull* dp = (ull*)((char*)hstate + gidx * 1024 + (size_t)l_in * 16);
      __hip_atomic_store(dp,     *(ull*)&v.x, __ATOMIC_RELAXED, __HIP_MEMORY_SCOPE_SYSTEM);
      __hip_atomic_store(dp + 1, *(ull*)&v.z, __ATOMIC_RELAXED, __HIP_MEMORY_SCOPE_SYSTEM);
      asm volatile("s_waitcnt vmcnt(0)" ::: "memory");   // h at LLC before flag
      if (lane == 0)
        __hip_atomic_store(flags + b, t + 1, __ATOMIC_RELAXED, __HIP_MEMORY_SCOPE_SYSTEM);
    }

    // ---- out store (HBM, fire-and-forget; overlaps next step's wait) ----
    out[((size_t)t * 1536 + hr0) * 64 + cg] = hv0;
    out[((size_t)t * 1536 + hr1) * 64 + cg] = hv1;
  }
}

// ============ host launcher ============
extern "C" void kernel_launch(void* const* d_in, const int* in_sizes, int n_in,
                              void* d_out, int out_size, void* d_ws, size_t ws_size,
                              hipStream_t stream) {
  (void)in_sizes; (void)n_in; (void)out_size;
  const float* x   = (const float*)d_in[0];
  const float* Wf  = (const float*)d_in[1];
  const float* bf_ = (const float*)d_in[2];
  const float* Wi  = (const float*)d_in[3];
  const float* bi_ = (const float*)d_in[4];
  const float* Wo  = (const float*)d_in[5];
  const float* bo_ = (const float*)d_in[6];
  const float* Wc  = (const float*)d_in[7];
  const float* bc_ = (const float*)d_in[8];
  const float* h0  = (const float*)d_in[9];
  const float* c0  = (const float*)d_in[10];

  if (ws_size < WS_NEEDED) return;   // diagnostic fail, not a crash

  char* ws = (char*)d_ws;
  uint16_t* wp = (uint16_t*)(ws + WP_OFF);
  uint16_t* xp = (uint16_t*)(ws + XP_OFF);
  uint16_t* gx = (uint16_t*)(ws + GX_OFF);
  uint16_t* hs = (uint16_t*)(ws + HS_OFF);
  int* flags   = (int*)(ws + FL_OFF);

  hipMemsetAsync(flags, 0, 1024, stream);
  pack_w<<<9216, 256, 0, stream>>>(Wf, Wi, Wo, Wc, wp);
  pack_xg<<<24576, 256, 0, stream>>>(x, xp);
  pack_h0<<<48, 256, 0, stream>>>(h0, hs);
  gemm_gx<<<12288, 256, 0, stream>>>(wp, xp, gx);

  lstm_persist<<<NWG, 256, 0, stream>>>(bf_, bi_, bo_, bc_, c0,
                                        wp, gx, hs, flags, (float*)d_out);
}

// Round 6
// 4435.514 us; speedup vs baseline: 2.5562x; 1.1433x over previous
//
#include <hip/hip_runtime.h>
#include <stdint.h>

#define TSTEPS 512
#define NWG 192

typedef short s8v __attribute__((ext_vector_type(8)));
typedef float f4v __attribute__((ext_vector_type(4)));
typedef unsigned long long ull;

// ---- workspace layout (bytes) ----
#define WP_BYTES  37748736ull               // packed weights bf16 (full K), fragment tiles
#define XP_BYTES 100663296ull               // packed x bf16 (GEMM B-granules)
#define GX_BYTES 402653184ull               // gx = Wx@x, bf16 [T][6144][64]
#define HS_BYTES    393216ull               // h state, 2 x 192 granules x 1KB
#define WP_OFF 0ull
#define XP_OFF 37748736ull
#define GX_OFF 138412032ull
#define HS_OFF (GX_OFF + GX_BYTES)
#define FL_OFF (HS_OFF + HS_BYTES)
#define WS_NEEDED (FL_OFF + 1024ull)        // ~516.6 MiB (proven available)

// persist LDS: 64KB partials + 1.5KB ht
#define PLDS_TOTAL (65536 + 1536)

__device__ __forceinline__ uint16_t f2bf(float f) {
  union { float f; uint32_t u; } v; v.f = f;
  uint32_t u = v.u;
  return (uint16_t)((u + 0x7fffu + ((u >> 16) & 1u)) >> 16);
}
__device__ __forceinline__ float bf2f(uint32_t u) {
  union { uint32_t u; float f; } v; v.u = u << 16;
  return v.f;
}
__device__ __forceinline__ float sigm(float x) { return 1.0f / (1.0f + __expf(-x)); }
__device__ __forceinline__ float tanh_fast(float x) {
  float e = __expf(2.0f * x);
  return 1.0f - 2.0f / (e + 1.0f);
}
__device__ __forceinline__ void gload_lds16(const void* g, void* l) {
  typedef __attribute__((address_space(1))) uint32_t g32;
  typedef __attribute__((address_space(3))) uint32_t l32;
  __builtin_amdgcn_global_load_lds((g32*)g, (l32*)l, 16, 0, 0);
}

// ============ prep kernels ============

// Pack W{f,i,o,c} fp32 [1536][3072] -> bf16 fragment tiles (full K).
// tile id = ((rg*96 + ks)*4 + g); lane l holds 16B =
// W_g[rg*16 + (l&15)][ks*32 + (l>>4)*8 + j], j=0..7
__global__ void pack_w(const float* __restrict__ Wf, const float* __restrict__ Wi,
                       const float* __restrict__ Wo, const float* __restrict__ Wc,
                       uint16_t* __restrict__ wp) {
  int tile = blockIdx.x * 4 + (threadIdx.x >> 6);
  int lane = threadIdx.x & 63;
  int g  = tile & 3;
  int ks = (tile >> 2) % 96;
  int rg = tile / 384;
  const float* W = (g == 0) ? Wf : (g == 1) ? Wi : (g == 2) ? Wo : Wc;
  int hr = rg * 16 + (lane & 15);
  int kk = ks * 32 + (lane >> 4) * 8;
  const float* src = W + (size_t)hr * 3072 + kk;
  uint32_t w[4];
#pragma unroll
  for (int j = 0; j < 4; ++j) {
    uint32_t lo = f2bf(src[2 * j]);
    uint32_t hi = f2bf(src[2 * j + 1]);
    w[j] = lo | (hi << 16);
  }
  *(uint4*)((char*)wp + (size_t)tile * 1024 + (size_t)lane * 16) = make_uint4(w[0], w[1], w[2], w[3]);
}

// Pack x as GEMM B-fragment granules. granule gi = n16*48 + ks;
// lane l: col n = n16*16 + (l&15) -> t=n>>6, b=n&63; k-row i = ks*32+(l>>4)*8+j
__global__ void pack_xg(const float* __restrict__ x, uint16_t* __restrict__ xg) {
  size_t gi4 = (size_t)blockIdx.x * 4 + (threadIdx.x >> 6);  // granule, < 98304
  int lane = threadIdx.x & 63;
  int n16 = (int)(gi4 / 48);
  int ks  = (int)(gi4 % 48);
  int n = n16 * 16 + (lane & 15);
  int t = n >> 6, bb = n & 63;
  int i0 = ks * 32 + (lane >> 4) * 8;
  const float* src = x + ((size_t)t * 1536 + i0) * 64 + bb;
  uint32_t w[4];
#pragma unroll
  for (int j = 0; j < 4; ++j) {
    uint32_t lo = f2bf(src[(size_t)(2 * j) * 64]);
    uint32_t hi = f2bf(src[(size_t)(2 * j + 1) * 64]);
    w[j] = lo | (hi << 16);
  }
  *(uint4*)((char*)xg + gi4 * 1024 + (size_t)lane * 16) = make_uint4(w[0], w[1], w[2], w[3]);
}

// h0 fp32 [1536][64] -> hstate[par=0] in granule layout:
// granule gr = (ch*48 + ks)*2 + cf; lane l holds 16B = bf16
// h[k = ks*32+(l>>4)*8+j][col = ch*32+cf*16+(l&15)], j=0..7
__global__ void pack_h0(const float* __restrict__ h0, uint16_t* __restrict__ hs) {
  int tg = blockIdx.x * 256 + threadIdx.x;    // < 12288
  int lane = tg & 63, gr = tg >> 6;           // gr < 192
  int cf = gr & 1, r2 = gr >> 1;
  int ks = r2 % 48, ch = r2 / 48;
  int col = ch * 32 + cf * 16 + (lane & 15);
  int k0 = ks * 32 + (lane >> 4) * 8;
  const float* src = h0 + (size_t)k0 * 64 + col;
  uint32_t w[4];
#pragma unroll
  for (int j = 0; j < 4; ++j) {
    uint32_t lo = f2bf(src[(size_t)(2 * j) * 64]);
    uint32_t hi = f2bf(src[(size_t)(2 * j + 1) * 64]);
    w[j] = lo | (hi << 16);
  }
  *(uint4*)((char*)hs + (size_t)gr * 1024 + (size_t)lane * 16) = make_uint4(w[0], w[1], w[2], w[3]);
}

// ============ gx = Wx @ X  (M=6144, N=32768, K=1536) ============
__global__ __launch_bounds__(256) void gemm_gx(const uint16_t* __restrict__ wp,
                                               const uint16_t* __restrict__ xg,
                                               uint16_t* __restrict__ gxp) {
  __shared__ char lds[32768];
  const int tid = threadIdx.x;
  const int lane = tid & 63, wave = tid >> 6;
  const int bid = blockIdx.x;
  const int mb = bid >> 8;                // 0..47
  const int nb = bid & 255;               // 0..255
  const int wm = wave >> 1, wn = wave & 1;

  const char* wpb = (const char*)wp;
  const char* xgb = (const char*)xg;
  const int g   = (mb * 8) / 96;
  const int rgb = (mb * 8) % 96;

  auto stage = [&](int ks, int buf) {
    char* Ad = lds + buf * 16384 + wave * 1024;
    char* Bd = lds + buf * 16384 + 8192 + wave * 1024;
#pragma unroll
    for (int p = 0; p < 2; ++p) {
      int l = wave + p * 4;
      size_t atile = ((size_t)(rgb + l) * 96 + 48 + ks) * 4 + g;
      gload_lds16(wpb + atile * 1024 + (size_t)lane * 16, Ad + p * 4096);
      size_t btile = (size_t)(nb * 8 + l) * 48 + ks;
      gload_lds16(xgb + btile * 1024 + (size_t)lane * 16, Bd + p * 4096);
    }
  };

  stage(0, 0);
  __syncthreads();

  f4v acc[4][4];
#pragma unroll
  for (int i = 0; i < 4; ++i)
#pragma unroll
    for (int j = 0; j < 4; ++j) acc[i][j] = f4v{0.f, 0.f, 0.f, 0.f};

  for (int ks = 0; ks < 48; ++ks) {
    int buf = ks & 1;
    if (ks < 47) stage(ks + 1, buf ^ 1);
    const char* Ab = lds + buf * 16384 + (size_t)(wm * 4) * 1024;
    const char* Bb = lds + buf * 16384 + 8192 + (size_t)(wn * 4) * 1024;
    uint4 af[4], bfr[4];
#pragma unroll
    for (int i = 0; i < 4; ++i) af[i]  = *(const uint4*)(Ab + (size_t)i * 1024 + (size_t)lane * 16);
#pragma unroll
    for (int j = 0; j < 4; ++j) bfr[j] = *(const uint4*)(Bb + (size_t)j * 1024 + (size_t)lane * 16);
#pragma unroll
    for (int i = 0; i < 4; ++i)
#pragma unroll
      for (int j = 0; j < 4; ++j)
        acc[i][j] = __builtin_amdgcn_mfma_f32_16x16x32_bf16(
            __builtin_bit_cast(s8v, af[i]), __builtin_bit_cast(s8v, bfr[j]), acc[i][j], 0, 0, 0);
    __syncthreads();
  }

#pragma unroll
  for (int i = 0; i < 4; ++i) {
    int m = (mb * 8 + wm * 4 + i) * 16 + (lane >> 4) * 4;
#pragma unroll
    for (int j = 0; j < 4; ++j) {
      int n = (nb * 8 + wn * 4 + j) * 16 + (lane & 15);
      int tt = n >> 6, bb = n & 63;
#pragma unroll
      for (int r = 0; r < 4; ++r)
        gxp[((size_t)tt * 6144 + m + r) * 64 + bb] = f2bf(acc[i][j][r]);
    }
  }
}

// ============ persistent LSTM kernel ============
// 192 blocks x 512 threads (8 waves, 2 waves/SIMD). block b: ch = b/96,
// rg = b%96 (rows rg*16..+15, cols ch*32..+31). K-split: wave w handles
// ks = w*6..w*6+5 for ALL 4 gates -> A = 24 tiles = 96 regs/lane (fits the
// 256-reg budget at launch_bounds(512,2), so weights stay register-resident;
// wp/hstate NOT __restrict__ so re-loading in-loop is illegal). h granules
// read with system-scope relaxed 8B loads (LLC-direct; no fence, L2 stays
// warm for gx). 8-wave partial reduce in 64KB LDS; 1 output/thread epilogue.
__global__ __launch_bounds__(512, 2) void lstm_persist(
    const float* __restrict__ bfp, const float* __restrict__ bip,
    const float* __restrict__ bop, const float* __restrict__ bcp,
    const float* __restrict__ c0p,
    const uint16_t* wp,              // NOT restrict: may-alias hstate
    const uint16_t* __restrict__ gxp,
    uint16_t* hstate,                // NOT restrict
    int* __restrict__ flags,
    float* __restrict__ out)
{
  extern __shared__ __align__(16) char smem[];        // 64KB partials | 1.5KB ht
  uint16_t* ht = (uint16_t*)(smem + 65536);           // [col][24] stride-24 bf16
  const int tid = threadIdx.x;
  const int wave = tid >> 6, lane = tid & 63;
  const int b = blockIdx.x;
  const int ch = b / 96, rg = b % 96;

  // epilogue mapping: 512 threads = 16 rows x 32 cols, one output each
  const int c = tid & 31, rr = (tid >> 5) & 15;
  const int hr = rg * 16 + rr;
  const int cg = ch * 32 + c;
  const int cfE = c >> 4, c15e = c & 15;
  // float idx in partials for (w=0,g=0): + w*2048 + g*512 + cfE*256
  const int rbase = cfE * 256 + ((rr >> 2) * 16 + c15e) * 4 + (rr & 3);

  float cst = c0p[(size_t)hr * 64 + cg];
  const float vb[4] = {bfp[hr], bip[hr], bop[hr], bcp[hr]};

  // ---- load this wave's 24 weight tiles into registers (live across t) ----
  uint4 Ar[6][4];
  {
    const char* wpb = (const char*)wp;
#pragma unroll
    for (int q = 0; q < 6; ++q)
#pragma unroll
      for (int g = 0; g < 4; ++g) {
        size_t tile = ((size_t)rg * 96 + wave * 6 + q) * 4 + g;
        Ar[q][g] = *(const uint4*)(wpb + tile * 1024 + (size_t)lane * 16);
      }
  }

  const char* hsb = (const char*)hstate;

  for (int t = 0; t < TSTEPS; ++t) {
    const int par = t & 1;

    // ---- gx prefetch (immutable; issued before the wait, overlaps poll) ----
    uint32_t gxr[4];
    {
      const uint16_t* gbase = gxp + ((size_t)t * 6144 + hr) * 64 + cg;
#pragma unroll
      for (int g = 0; g < 4; ++g)
        gxr[g] = gbase[(size_t)g * 1536 * 64];
    }

    // ---- wave0 polls the 96 same-ch flags; barrier releases the block ----
    if (t > 0 && wave == 0) {
      const int need = t;
      const ull* fb = (const ull*)(flags + ch * 96);
      for (;;) {
        int ok = 1;
        if (lane < 48) {
          ull a = __hip_atomic_load(fb + lane, __ATOMIC_RELAXED, __HIP_MEMORY_SCOPE_SYSTEM);
          int f0 = (int)(unsigned)a, f1 = (int)(a >> 32);
          ok = (f0 >= need) & (f1 >= need);
        }
        if (__all(ok)) break;
        __builtin_amdgcn_s_sleep(1);
      }
    }
    __syncthreads();   // release: h for step t is at LLC

    // ---- B granules: system-scope (LLC-direct) loads into registers ----
    uint4 Bg[6][2];
    {
      const char* base = hsb + (((size_t)(par * 2 + ch) * 48 + wave * 6) * 2) * 1024
                             + (size_t)lane * 16;
#pragma unroll
      for (int q = 0; q < 6; ++q) {
#pragma unroll
        for (int cf = 0; cf < 2; ++cf) {
          const ull* p = (const ull*)(base + (size_t)q * 2048 + (size_t)cf * 1024);
          ull lo = __hip_atomic_load(p,     __ATOMIC_RELAXED, __HIP_MEMORY_SCOPE_SYSTEM);
          ull hi = __hip_atomic_load(p + 1, __ATOMIC_RELAXED, __HIP_MEMORY_SCOPE_SYSTEM);
          uint4 v;
          *(ull*)&v.x = lo;
          *(ull*)&v.z = hi;
          Bg[q][cf] = v;
        }
      }
    }

    // ---- MFMA: 48 per wave, all operands in registers ----
    f4v acc[4][2];
#pragma unroll
    for (int g = 0; g < 4; ++g)
#pragma unroll
      for (int cf = 0; cf < 2; ++cf) acc[g][cf] = f4v{0.f, 0.f, 0.f, 0.f};
#pragma unroll
    for (int q = 0; q < 6; ++q)
#pragma unroll
      for (int g = 0; g < 4; ++g)
#pragma unroll
        for (int cf = 0; cf < 2; ++cf)
          acc[g][cf] = __builtin_amdgcn_mfma_f32_16x16x32_bf16(
              __builtin_bit_cast(s8v, Ar[q][g]), __builtin_bit_cast(s8v, Bg[q][cf]),
              acc[g][cf], 0, 0, 0);

    // ---- write partials to LDS: [w][g][cf][lane] x 16B ----
#pragma unroll
    for (int g = 0; g < 4; ++g)
#pragma unroll
      for (int cf = 0; cf < 2; ++cf)
        *(uint4*)(smem + (((size_t)wave * 8 + g * 2 + cf) * 64 + lane) * 16)
            = __builtin_bit_cast(uint4, acc[g][cf]);
    __syncthreads();   // reduction barrier

    // ---- reduce 8 waves + gates epilogue (1 output/thread) ----
    float hv;
    {
      const float* P = (const float*)smem;
      float s[4];
#pragma unroll
      for (int g = 0; g < 4; ++g) {
        int i0 = rbase + g * 512;
        float a0 = P[i0]          + P[i0 + 2048];
        float a1 = P[i0 + 4096]   + P[i0 + 6144];
        float a2 = P[i0 + 8192]   + P[i0 + 10240];
        float a3 = P[i0 + 12288]  + P[i0 + 14336];
        s[g] = (a0 + a1) + (a2 + a3);
      }
      float pf = s[0] + vb[0] + bf2f(gxr[0]);
      float pi = s[1] + vb[1] + bf2f(gxr[1]);
      float po = s[2] + vb[2] + bf2f(gxr[2]);
      float pc = s[3] + vb[3] + bf2f(gxr[3]);
      float f = sigm(pf), ii = sigm(pi), o = sigm(po), cc = tanh_fast(pc);
      cst = f * cst + ii * cc;
      hv = o * tanh_fast(cst);
    }

    // ---- transpose h into LDS (stride-24 bf16) ----
    ht[c * 24 + rr] = f2bf(hv);
    __syncthreads();   // partials consumed, ht complete

    // ---- wave 0: publish h granule-halves (system scope) + flag ----
    // out stores are issued AFTER the flag so vmcnt(0) drains only h stores.
    if (wave == 0) {
      int cf2 = lane >> 5, hh = (lane >> 4) & 1, c15 = lane & 15;
      uint4 v = *(const uint4*)(ht + (cf2 * 16 + c15) * 24 + hh * 8);
      size_t gidx = ((size_t)((par ^ 1) * 2 + ch) * 48 + (rg >> 1)) * 2 + cf2;
      int l_in = ((rg & 1) * 2 + hh) * 16 + c15;
      ull* dp = (ull*)((char*)hstate + gidx * 1024 + (size_t)l_in * 16);
      __hip_atomic_store(dp,     *(ull*)&v.x, __ATOMIC_RELAXED, __HIP_MEMORY_SCOPE_SYSTEM);
      __hip_atomic_store(dp + 1, *(ull*)&v.z, __ATOMIC_RELAXED, __HIP_MEMORY_SCOPE_SYSTEM);
      asm volatile("s_waitcnt vmcnt(0)" ::: "memory");   // h at LLC before flag
      if (lane == 0)
        __hip_atomic_store(flags + b, t + 1, __ATOMIC_RELAXED, __HIP_MEMORY_SCOPE_SYSTEM);
    }

    // ---- out store (HBM, fire-and-forget; overlaps next step's wait) ----
    out[((size_t)t * 1536 + hr) * 64 + cg] = hv;
  }
}

// ============ host launcher ============
extern "C" void kernel_launch(void* const* d_in, const int* in_sizes, int n_in,
                              void* d_out, int out_size, void* d_ws, size_t ws_size,
                              hipStream_t stream) {
  (void)in_sizes; (void)n_in; (void)out_size;
  const float* x   = (const float*)d_in[0];
  const float* Wf  = (const float*)d_in[1];
  const float* bf_ = (const float*)d_in[2];
  const float* Wi  = (const float*)d_in[3];
  const float* bi_ = (const float*)d_in[4];
  const float* Wo  = (const float*)d_in[5];
  const float* bo_ = (const float*)d_in[6];
  const float* Wc  = (const float*)d_in[7];
  const float* bc_ = (const float*)d_in[8];
  const float* h0  = (const float*)d_in[9];
  const float* c0  = (const float*)d_in[10];

  if (ws_size < WS_NEEDED) return;   // diagnostic fail, not a crash

  char* ws = (char*)d_ws;
  uint16_t* wp = (uint16_t*)(ws + WP_OFF);
  uint16_t* xp = (uint16_t*)(ws + XP_OFF);
  uint16_t* gx = (uint16_t*)(ws + GX_OFF);
  uint16_t* hs = (uint16_t*)(ws + HS_OFF);
  int* flags   = (int*)(ws + FL_OFF);

  hipMemsetAsync(flags, 0, 1024, stream);
  pack_w<<<9216, 256, 0, stream>>>(Wf, Wi, Wo, Wc, wp);
  pack_xg<<<24576, 256, 0, stream>>>(x, xp);
  pack_h0<<<48, 256, 0, stream>>>(h0, hs);
  gemm_gx<<<12288, 256, 0, stream>>>(wp, xp, gx);

  hipFuncSetAttribute(reinterpret_cast<const void*>(lstm_persist),
                      hipFuncAttributeMaxDynamicSharedMemorySize, PLDS_TOTAL);
  lstm_persist<<<NWG, 512, PLDS_TOTAL, stream>>>(bf_, bi_, bo_, bc_, c0,
                                                 wp, gx, hs, flags, (float*)d_out);
}

// Round 7
// 3998.338 us; speedup vs baseline: 2.8357x; 1.1093x over previous
//
#include <hip/hip_runtime.h>
#include <stdint.h>

#define TSTEPS 512
#define NWG 192

typedef short s8v __attribute__((ext_vector_type(8)));
typedef float f4v __attribute__((ext_vector_type(4)));
typedef unsigned long long ull;

// ---- workspace layout (bytes) ----
#define WP_BYTES  37748736ull               // packed weights bf16 (full K), fragment tiles
#define XP_BYTES 100663296ull               // packed x bf16 (GEMM B-granules)
#define GX_BYTES 402653184ull               // gx = Wx@x, bf16 [T][6144][64]
#define HS_BYTES    393216ull               // h state, 2 x 192 granules x 1KB
#define WP_OFF 0ull
#define XP_OFF 37748736ull
#define GX_OFF 138412032ull
#define HS_OFF (GX_OFF + GX_BYTES)
#define FL_OFF (HS_OFF + HS_BYTES)
#define WS_NEEDED (FL_OFF + 1024ull)        // ~516.6 MiB (proven available)

// persist LDS: 64KB partials + 1.5KB ht
#define PLDS_TOTAL (65536 + 1536)

__device__ __forceinline__ uint16_t f2bf(float f) {
  union { float f; uint32_t u; } v; v.f = f;
  uint32_t u = v.u;
  return (uint16_t)((u + 0x7fffu + ((u >> 16) & 1u)) >> 16);
}
__device__ __forceinline__ float bf2f(uint32_t u) {
  union { uint32_t u; float f; } v; v.u = u << 16;
  return v.f;
}
__device__ __forceinline__ float sigm(float x) { return 1.0f / (1.0f + __expf(-x)); }
__device__ __forceinline__ float tanh_fast(float x) {
  float e = __expf(2.0f * x);
  return 1.0f - 2.0f / (e + 1.0f);
}
__device__ __forceinline__ void gload_lds16(const void* g, void* l) {
  typedef __attribute__((address_space(1))) uint32_t g32;
  typedef __attribute__((address_space(3))) uint32_t l32;
  __builtin_amdgcn_global_load_lds((g32*)g, (l32*)l, 16, 0, 0);
}

// ============ prep kernels ============

// Pack W{f,i,o,c} fp32 [1536][3072] -> bf16 fragment tiles (full K).
// tile id = ((rg*96 + ks)*4 + g); lane l holds 16B =
// W_g[rg*16 + (l&15)][ks*32 + (l>>4)*8 + j], j=0..7
__global__ void pack_w(const float* __restrict__ Wf, const float* __restrict__ Wi,
                       const float* __restrict__ Wo, const float* __restrict__ Wc,
                       uint16_t* __restrict__ wp) {
  int tile = blockIdx.x * 4 + (threadIdx.x >> 6);
  int lane = threadIdx.x & 63;
  int g  = tile & 3;
  int ks = (tile >> 2) % 96;
  int rg = tile / 384;
  const float* W = (g == 0) ? Wf : (g == 1) ? Wi : (g == 2) ? Wo : Wc;
  int hr = rg * 16 + (lane & 15);
  int kk = ks * 32 + (lane >> 4) * 8;
  const float* src = W + (size_t)hr * 3072 + kk;
  uint32_t w[4];
#pragma unroll
  for (int j = 0; j < 4; ++j) {
    uint32_t lo = f2bf(src[2 * j]);
    uint32_t hi = f2bf(src[2 * j + 1]);
    w[j] = lo | (hi << 16);
  }
  *(uint4*)((char*)wp + (size_t)tile * 1024 + (size_t)lane * 16) = make_uint4(w[0], w[1], w[2], w[3]);
}

// Pack x as GEMM B-fragment granules. granule gi = n16*48 + ks;
// lane l: col n = n16*16 + (l&15) -> t=n>>6, b=n&63; k-row i = ks*32+(l>>4)*8+j
__global__ void pack_xg(const float* __restrict__ x, uint16_t* __restrict__ xg) {
  size_t gi4 = (size_t)blockIdx.x * 4 + (threadIdx.x >> 6);  // granule, < 98304
  int lane = threadIdx.x & 63;
  int n16 = (int)(gi4 / 48);
  int ks  = (int)(gi4 % 48);
  int n = n16 * 16 + (lane & 15);
  int t = n >> 6, bb = n & 63;
  int i0 = ks * 32 + (lane >> 4) * 8;
  const float* src = x + ((size_t)t * 1536 + i0) * 64 + bb;
  uint32_t w[4];
#pragma unroll
  for (int j = 0; j < 4; ++j) {
    uint32_t lo = f2bf(src[(size_t)(2 * j) * 64]);
    uint32_t hi = f2bf(src[(size_t)(2 * j + 1) * 64]);
    w[j] = lo | (hi << 16);
  }
  *(uint4*)((char*)xg + gi4 * 1024 + (size_t)lane * 16) = make_uint4(w[0], w[1], w[2], w[3]);
}

// h0 fp32 [1536][64] -> hstate[par=0] in granule layout:
// granule gr = (ch*48 + ks)*2 + cf; lane l holds 16B = bf16
// h[k = ks*32+(l>>4)*8+j][col = ch*32+cf*16+(l&15)], j=0..7
__global__ void pack_h0(const float* __restrict__ h0, uint16_t* __restrict__ hs) {
  int tg = blockIdx.x * 256 + threadIdx.x;    // < 12288
  int lane = tg & 63, gr = tg >> 6;           // gr < 192
  int cf = gr & 1, r2 = gr >> 1;
  int ks = r2 % 48, ch = r2 / 48;
  int col = ch * 32 + cf * 16 + (lane & 15);
  int k0 = ks * 32 + (lane >> 4) * 8;
  const float* src = h0 + (size_t)k0 * 64 + col;
  uint32_t w[4];
#pragma unroll
  for (int j = 0; j < 4; ++j) {
    uint32_t lo = f2bf(src[(size_t)(2 * j) * 64]);
    uint32_t hi = f2bf(src[(size_t)(2 * j + 1) * 64]);
    w[j] = lo | (hi << 16);
  }
  *(uint4*)((char*)hs + (size_t)gr * 1024 + (size_t)lane * 16) = make_uint4(w[0], w[1], w[2], w[3]);
}

// ============ gx = Wx @ X  (M=6144, N=32768, K=1536) ============
__global__ __launch_bounds__(256) void gemm_gx(const uint16_t* __restrict__ wp,
                                               const uint16_t* __restrict__ xg,
                                               uint16_t* __restrict__ gxp) {
  __shared__ char lds[32768];
  const int tid = threadIdx.x;
  const int lane = tid & 63, wave = tid >> 6;
  const int bid = blockIdx.x;
  const int mb = bid >> 8;                // 0..47
  const int nb = bid & 255;               // 0..255
  const int wm = wave >> 1, wn = wave & 1;

  const char* wpb = (const char*)wp;
  const char* xgb = (const char*)xg;
  const int g   = (mb * 8) / 96;
  const int rgb = (mb * 8) % 96;

  auto stage = [&](int ks, int buf) {
    char* Ad = lds + buf * 16384 + wave * 1024;
    char* Bd = lds + buf * 16384 + 8192 + wave * 1024;
#pragma unroll
    for (int p = 0; p < 2; ++p) {
      int l = wave + p * 4;
      size_t atile = ((size_t)(rgb + l) * 96 + 48 + ks) * 4 + g;
      gload_lds16(wpb + atile * 1024 + (size_t)lane * 16, Ad + p * 4096);
      size_t btile = (size_t)(nb * 8 + l) * 48 + ks;
      gload_lds16(xgb + btile * 1024 + (size_t)lane * 16, Bd + p * 4096);
    }
  };

  stage(0, 0);
  __syncthreads();

  f4v acc[4][4];
#pragma unroll
  for (int i = 0; i < 4; ++i)
#pragma unroll
    for (int j = 0; j < 4; ++j) acc[i][j] = f4v{0.f, 0.f, 0.f, 0.f};

  for (int ks = 0; ks < 48; ++ks) {
    int buf = ks & 1;
    if (ks < 47) stage(ks + 1, buf ^ 1);
    const char* Ab = lds + buf * 16384 + (size_t)(wm * 4) * 1024;
    const char* Bb = lds + buf * 16384 + 8192 + (size_t)(wn * 4) * 1024;
    uint4 af[4], bfr[4];
#pragma unroll
    for (int i = 0; i < 4; ++i) af[i]  = *(const uint4*)(Ab + (size_t)i * 1024 + (size_t)lane * 16);
#pragma unroll
    for (int j = 0; j < 4; ++j) bfr[j] = *(const uint4*)(Bb + (size_t)j * 1024 + (size_t)lane * 16);
#pragma unroll
    for (int i = 0; i < 4; ++i)
#pragma unroll
      for (int j = 0; j < 4; ++j)
        acc[i][j] = __builtin_amdgcn_mfma_f32_16x16x32_bf16(
            __builtin_bit_cast(s8v, af[i]), __builtin_bit_cast(s8v, bfr[j]), acc[i][j], 0, 0, 0);
    __syncthreads();
  }

#pragma unroll
  for (int i = 0; i < 4; ++i) {
    int m = (mb * 8 + wm * 4 + i) * 16 + (lane >> 4) * 4;
#pragma unroll
    for (int j = 0; j < 4; ++j) {
      int n = (nb * 8 + wn * 4 + j) * 16 + (lane & 15);
      int tt = n >> 6, bb = n & 63;
#pragma unroll
      for (int r = 0; r < 4; ++r)
        gxp[((size_t)tt * 6144 + m + r) * 64 + bb] = f2bf(acc[i][j][r]);
    }
  }
}

// ============ persistent LSTM kernel ============
// 192 blocks x 512 threads (8 waves, 2 waves/SIMD). block b: ch = b/96,
// rg = b%96 (rows rg*16..+15, cols ch*32..+31). K-split: wave w handles
// ks = w*6..w*6+5 for ALL 4 gates. Weights are STREAMED per step from wp
// (L2-shared: b and b+96 land on the same XCD and read the same slice),
// issued BEFORE the flag poll so __syncthreads' vmcnt(0) drain overlaps
// the wait. Intra-iteration live range -> no spill (round-6 lesson: the
// allocator will NOT hold ~100 loop-carried regs; it spills to scratch).
// wp/hstate NOT __restrict__ so the pre-barrier loads can't sink past the
// barrier. h granules: system-scope relaxed 8B loads (LLC-direct, no
// fence/inv — L2 stays warm). 8-wave partial reduce in 64KB LDS.
__global__ __launch_bounds__(512, 2) void lstm_persist(
    const float* __restrict__ bfp, const float* __restrict__ bip,
    const float* __restrict__ bop, const float* __restrict__ bcp,
    const float* __restrict__ c0p,
    const uint16_t* wp,              // NOT restrict: may-alias hstate
    const uint16_t* __restrict__ gxp,
    uint16_t* hstate,                // NOT restrict
    int* __restrict__ flags,
    float* __restrict__ out)
{
  extern __shared__ __align__(16) char smem[];        // 64KB partials | 1.5KB ht
  uint16_t* ht = (uint16_t*)(smem + 65536);           // [col][24] stride-24 bf16
  const int tid = threadIdx.x;
  const int wave = tid >> 6, lane = tid & 63;
  const int b = blockIdx.x;
  const int ch = b / 96, rg = b % 96;

  // epilogue mapping: 512 threads = 16 rows x 32 cols, one output each
  const int c = tid & 31, rr = (tid >> 5) & 15;
  const int hr = rg * 16 + rr;
  const int cg = ch * 32 + c;
  const int cfE = c >> 4, c15e = c & 15;
  // float idx in partials for (w=0,g=0): + w*2048 + g*512 + cfE*256
  const int rbase = cfE * 256 + ((rr >> 2) * 16 + c15e) * 4 + (rr & 3);

  float cst = c0p[(size_t)hr * 64 + cg];
  const float vb[4] = {bfp[hr], bip[hr], bop[hr], bcp[hr]};

  // per-wave weight base (24 tiles re-read each step, L2-resident, shared)
  const char* wpb = (const char*)wp
                  + ((size_t)rg * 96 + wave * 6) * 4096 + (size_t)lane * 16;
  const char* hsb = (const char*)hstate;

  for (int t = 0; t < TSTEPS; ++t) {
    const int par = t & 1;

    // ---- pre-issue loads that do NOT depend on h(t): they complete during
    //      the poll (syncthreads drains vmcnt before s_barrier) ----
    // gx (HBM-resident, longest latency — issue first)
    uint32_t gxr[4];
    {
      const uint16_t* gbase = gxp + ((size_t)t * 6144 + hr) * 64 + cg;
#pragma unroll
      for (int g = 0; g < 4; ++g)
        gxr[g] = gbase[(size_t)g * 1536 * 64];
    }
    // weights: 24 x 16B per lane from wp (L2-shared with the b+/-96 twin)
    uint4 Ar[6][4];
#pragma unroll
    for (int q = 0; q < 6; ++q)
#pragma unroll
      for (int g = 0; g < 4; ++g)
        Ar[q][g] = *(const uint4*)(wpb + (size_t)(q * 4 + g) * 1024);

    // ---- wave0 polls the 96 same-ch flags; barrier releases the block ----
    if (t > 0 && wave == 0) {
      const int need = t;
      const ull* fb = (const ull*)(flags + ch * 96);
      for (;;) {
        int ok = 1;
        if (lane < 48) {
          ull a = __hip_atomic_load(fb + lane, __ATOMIC_RELAXED, __HIP_MEMORY_SCOPE_SYSTEM);
          int f0 = (int)(unsigned)a, f1 = (int)(a >> 32);
          ok = (f0 >= need) & (f1 >= need);
        }
        if (__all(ok)) break;
        __builtin_amdgcn_s_sleep(1);
      }
    }
    __syncthreads();   // release: h for step t is at LLC; Ar/gx drained

    // ---- B granules: system-scope (LLC-direct) loads into registers ----
    uint4 Bg[6][2];
    {
      const char* base = hsb + (((size_t)(par * 2 + ch) * 48 + wave * 6) * 2) * 1024
                             + (size_t)lane * 16;
#pragma unroll
      for (int q = 0; q < 6; ++q) {
#pragma unroll
        for (int cf = 0; cf < 2; ++cf) {
          const ull* p = (const ull*)(base + (size_t)q * 2048 + (size_t)cf * 1024);
          ull lo = __hip_atomic_load(p,     __ATOMIC_RELAXED, __HIP_MEMORY_SCOPE_SYSTEM);
          ull hi = __hip_atomic_load(p + 1, __ATOMIC_RELAXED, __HIP_MEMORY_SCOPE_SYSTEM);
          uint4 v;
          *(ull*)&v.x = lo;
          *(ull*)&v.z = hi;
          Bg[q][cf] = v;
        }
      }
    }

    // ---- MFMA: 48 per wave, all operands in registers ----
    f4v acc[4][2];
#pragma unroll
    for (int g = 0; g < 4; ++g)
#pragma unroll
      for (int cf = 0; cf < 2; ++cf) acc[g][cf] = f4v{0.f, 0.f, 0.f, 0.f};
#pragma unroll
    for (int q = 0; q < 6; ++q)
#pragma unroll
      for (int g = 0; g < 4; ++g)
#pragma unroll
        for (int cf = 0; cf < 2; ++cf)
          acc[g][cf] = __builtin_amdgcn_mfma_f32_16x16x32_bf16(
              __builtin_bit_cast(s8v, Ar[q][g]), __builtin_bit_cast(s8v, Bg[q][cf]),
              acc[g][cf], 0, 0, 0);

    // ---- write partials to LDS: [w][g][cf][lane] x 16B ----
#pragma unroll
    for (int g = 0; g < 4; ++g)
#pragma unroll
      for (int cf = 0; cf < 2; ++cf)
        *(uint4*)(smem + (((size_t)wave * 8 + g * 2 + cf) * 64 + lane) * 16)
            = __builtin_bit_cast(uint4, acc[g][cf]);
    __syncthreads();   // reduction barrier

    // ---- reduce 8 waves + gates epilogue (1 output/thread) ----
    float hv;
    {
      const float* P = (const float*)smem;
      float s[4];
#pragma unroll
      for (int g = 0; g < 4; ++g) {
        int i0 = rbase + g * 512;
        float a0 = P[i0]          + P[i0 + 2048];
        float a1 = P[i0 + 4096]   + P[i0 + 6144];
        float a2 = P[i0 + 8192]   + P[i0 + 10240];
        float a3 = P[i0 + 12288]  + P[i0 + 14336];
        s[g] = (a0 + a1) + (a2 + a3);
      }
      float pf = s[0] + vb[0] + bf2f(gxr[0]);
      float pi = s[1] + vb[1] + bf2f(gxr[1]);
      float po = s[2] + vb[2] + bf2f(gxr[2]);
      float pc = s[3] + vb[3] + bf2f(gxr[3]);
      float f = sigm(pf), ii = sigm(pi), o = sigm(po), cc = tanh_fast(pc);
      cst = f * cst + ii * cc;
      hv = o * tanh_fast(cst);
    }

    // ---- transpose h into LDS (stride-24 bf16) ----
    ht[c * 24 + rr] = f2bf(hv);
    __syncthreads();   // partials consumed, ht complete

    // ---- wave 0: publish h granule-halves (system scope) + flag ----
    // out stores are issued AFTER the flag so vmcnt(0) drains only h stores.
    if (wave == 0) {
      int cf2 = lane >> 5, hh = (lane >> 4) & 1, c15 = lane & 15;
      uint4 v = *(const uint4*)(ht + (cf2 * 16 + c15) * 24 + hh * 8);
      size_t gidx = ((size_t)((par ^ 1) * 2 + ch) * 48 + (rg >> 1)) * 2 + cf2;
      int l_in = ((rg & 1) * 2 + hh) * 16 + c15;
      ull* dp = (ull*)((char*)hstate + gidx * 1024 + (size_t)l_in * 16);
      __hip_atomic_store(dp,     *(ull*)&v.x, __ATOMIC_RELAXED, __HIP_MEMORY_SCOPE_SYSTEM);
      __hip_atomic_store(dp + 1, *(ull*)&v.z, __ATOMIC_RELAXED, __HIP_MEMORY_SCOPE_SYSTEM);
      asm volatile("s_waitcnt vmcnt(0)" ::: "memory");   // h at LLC before flag
      if (lane == 0)
        __hip_atomic_store(flags + b, t + 1, __ATOMIC_RELAXED, __HIP_MEMORY_SCOPE_SYSTEM);
    }

    // ---- out store (HBM, fire-and-forget; overlaps next step's wait) ----
    out[((size_t)t * 1536 + hr) * 64 + cg] = hv;
  }
}

// ============ host launcher ============
extern "C" void kernel_launch(void* const* d_in, const int* in_sizes, int n_in,
                              void* d_out, int out_size, void* d_ws, size_t ws_size,
                              hipStream_t stream) {
  (void)in_sizes; (void)n_in; (void)out_size;
  const float* x   = (const float*)d_in[0];
  const float* Wf  = (const float*)d_in[1];
  const float* bf_ = (const float*)d_in[2];
  const float* Wi  = (const float*)d_in[3];
  const float* bi_ = (const float*)d_in[4];
  const float* Wo  = (const float*)d_in[5];
  const float* bo_ = (const float*)d_in[6];
  const float* Wc  = (const float*)d_in[7];
  const float* bc_ = (const float*)d_in[8];
  const float* h0  = (const float*)d_in[9];
  const float* c0  = (const float*)d_in[10];

  if (ws_size < WS_NEEDED) return;   // diagnostic fail, not a crash

  char* ws = (char*)d_ws;
  uint16_t* wp = (uint16_t*)(ws + WP_OFF);
  uint16_t* xp = (uint16_t*)(ws + XP_OFF);
  uint16_t* gx = (uint16_t*)(ws + GX_OFF);
  uint16_t* hs = (uint16_t*)(ws + HS_OFF);
  int* flags   = (int*)(ws + FL_OFF);

  hipMemsetAsync(flags, 0, 1024, stream);
  pack_w<<<9216, 256, 0, stream>>>(Wf, Wi, Wo, Wc, wp);
  pack_xg<<<24576, 256, 0, stream>>>(x, xp);
  pack_h0<<<48, 256, 0, stream>>>(h0, hs);
  gemm_gx<<<12288, 256, 0, stream>>>(wp, xp, gx);

  hipFuncSetAttribute(reinterpret_cast<const void*>(lstm_persist),
                      hipFuncAttributeMaxDynamicSharedMemorySize, PLDS_TOTAL);
  lstm_persist<<<NWG, 512, PLDS_TOTAL, stream>>>(bf_, bi_, bo_, bc_, c0,
                                                 wp, gx, hs, flags, (float*)d_out);
}